// Round 3
// baseline (279.944 us; speedup 1.0000x reference)
//
#include <hip/hip_runtime.h>
#include <hip/hip_bf16.h>

#define CHN 512
#define TLEN 2048
#define KSZ 5
#define BATCH 16

typedef __hip_bfloat16 bf16;
typedef short bf16x8 __attribute__((ext_vector_type(8)));   // 8 bf16 (4 VGPRs)
typedef float f32x4  __attribute__((ext_vector_type(4)));

// ws layout:
//   samp : float2[B*T*5]  (pos, sig)       = 1,310,720 B
//   w1t  : bf16 [16][3][256][40]           =   983,040 B   (pre-tiled W1)
//   wpk  : float[512][32]                  =    65,536 B   (packed ow+mw)
#define SAMP_BYTES (BATCH*TLEN*KSZ*8)
#define W1T_BYTES  (983040)
#define W1T_ELEMS  (16*3*256*40)

// ---------------------------------------------------------------------------
// kPrep: fused kP (w1 retile, 1920 blocks) + kW (ow/mw pack, 64 blocks) +
//        kZ (outs = b2, 128 blocks). One dispatch instead of three.
// ---------------------------------------------------------------------------
__global__ __launch_bounds__(256) void kPrep(const float* __restrict__ w1,
    bf16* __restrict__ w1t, const float* __restrict__ ow,
    const float* __restrict__ mw, float* __restrict__ wpk,
    float* __restrict__ outs, const float* __restrict__ b2p)
{
  int bx = blockIdx.x;
  int tidl = threadIdx.x;
  if (bx < 1920) {
    // kP: w1 fp32 [co][ci][r] -> w1t bf16 [ch][r][co][40] (32 data + 8 pad)
    int idx  = bx*256 + tidl;                    // < 491520
    int c40  = idx % 40;
    int rest = idx / 40;
    int co   = rest & 255;
    int rr   = rest >> 8;          // ch*3 + r
    int r    = rr % 3;
    int ch   = rr / 3;
    float v = 0.f;
    if (c40 < 32) v = w1[(size_t)co*(CHN*3) + (ch*32 + c40)*3 + r];
    w1t[idx] = __float2bfloat16(v);
  } else if (bx < 1984) {
    // kW: pack ow/mw -> wpk[c][32]
    int idx = (bx-1920)*256 + tidl;              // < 16384
    int j = idx & 31, c = idx >> 5;
    float v = 0.f;
    if (j < 15)      { int o = j/3,  d = j - o*3;  v = ow[o*(CHN*3) + c*3 + d]; }
    else if (j < 30) { int jj = j-15; int o = jj/3, d = jj - o*3;
                       v = mw[o*(CHN*3) + c*3 + d]; }
    wpk[idx] = v;
  } else {
    // kZ: outs = b2 (k2 blocks atomically accumulate on top)
    outs[(bx-1984)*256 + tidl] = b2p[0];
  }
}

// ---------------------------------------------------------------------------
// kS: offset conv (out 0..4) + modulator conv (+sigmoid) -> sampling params.
// grid (TLEN/64, B), block (64 t, 8 cg). Each thread reduces 64 channels.
// samp[b,t,k] = (pos, sig); kDf re-derives base/wf/wc (bitwise-identical).
// ---------------------------------------------------------------------------
__global__ __launch_bounds__(512) void kS(const float* __restrict__ x,
    const float* __restrict__ wpk, const float* __restrict__ ob,
    const float* __restrict__ mb, float2* __restrict__ samp)
{
  int b  = blockIdx.y;
  int t0 = blockIdx.x*64;
  int tx = threadIdx.x;
  int cg = threadIdx.y;            // 0..7 (wave-uniform: wave = one tx row)
  int t  = t0 + tx;

  __shared__ float red[8][64][10];

  float acc[10];
  #pragma unroll
  for (int i=0;i<10;++i) acc[i]=0.f;
  const float* xb = x + (size_t)b*CHN*TLEN;
  int c0 = cg*64;
  #pragma unroll 4
  for (int c=c0;c<c0+64;++c) {
    int cu = __builtin_amdgcn_readfirstlane(c);
    const float* wp = wpk + cu*32;             // scalar -> s_load_dwordx8
    const float* xr = xb + (size_t)cu*TLEN;
    float xm = (t>0)      ? xr[t-1] : 0.f;
    float xc = xr[t];
    float xp = (t<TLEN-1) ? xr[t+1] : 0.f;
    #pragma unroll
    for (int o=0;o<5;++o) {
      acc[o]   = fmaf(xm, wp[o*3+0],    acc[o]);
      acc[o]   = fmaf(xc, wp[o*3+1],    acc[o]);
      acc[o]   = fmaf(xp, wp[o*3+2],    acc[o]);
      acc[5+o] = fmaf(xm, wp[15+o*3+0], acc[5+o]);
      acc[5+o] = fmaf(xc, wp[15+o*3+1], acc[5+o]);
      acc[5+o] = fmaf(xp, wp[15+o*3+2], acc[5+o]);
    }
  }
  #pragma unroll
  for (int i=0;i<10;++i) red[cg][tx][i] = acc[i];
  __syncthreads();
  for (int s=4;s>0;s>>=1) {
    if (cg < s) {
      #pragma unroll
      for (int i=0;i<10;++i) red[cg][tx][i] += red[cg+s][tx][i];
    }
    __syncthreads();
  }
  if (cg==0) {
    #pragma unroll
    for (int k=0;k<KSZ;++k) {
      float off = red[0][tx][k]   + ob[k];
      float mv  = red[0][tx][5+k] + mb[k];
      float sig = 1.f/(1.f + expf(-mv));
      float pos = (float)(t + k - 2) + off;
      pos = fminf(fmaxf(pos, 0.f), (float)(TLEN-1));
      samp[((size_t)b*TLEN + t)*KSZ + k] = make_float2(pos, sig);
    }
  }
}

// ---------------------------------------------------------------------------
// kDf: deformable sampling w/ diagonal weight — LDS-tiled.
// grid (T/128, C/64, B), block (64,4). Block stages x[c0..c0+63][lo..lo+159]
// into LDS via global_load_lds DMA (coalesced), then serves all gathers from
// LDS. Thread owns t = t0 + j*64 + tx (lane-consecutive) x 16 c-rows.
// Block-uniform fallback to global gathers if any base escapes the halo.
// ---------------------------------------------------------------------------
#define BT   128
#define HALO 16
#define XLEN 160   // BT + 2*HALO

__global__ __launch_bounds__(256) void kDf(const float* __restrict__ x,
    const float* __restrict__ wgt, const float2* __restrict__ sampg,
    float* __restrict__ out)
{
  int b  = blockIdx.z;
  int c0 = blockIdx.y*64;
  int t0 = blockIdx.x*BT;
  int tx = threadIdx.x, cy = threadIdx.y;
  int tid = cy*64 + tx;

  __shared__ float  xs[64*XLEN];    // 40,960 B
  __shared__ float2 sp[BT*KSZ];     //  5,120 B
  __shared__ int okf;

  int lo = min(max(t0 - HALO, 0), TLEN - XLEN);   // window always in-bounds

  if (tid == 0) okf = 1;
  for (int i = tid; i < BT*KSZ; i += 256)
    sp[i] = sampg[((size_t)b*TLEN + t0)*KSZ + i];

  // --- DMA x tile: 64 rows x 160 floats = 2560 float4 chunks, 10/thread.
  const float* xb = x + (size_t)b*CHN*TLEN;
  #pragma unroll
  for (int it = 0; it < 10; ++it) {
    int idx = tid + it*256;
    int c  = idx / 40;             // local c row
    int c4 = idx - c*40;           // float4 within row
    const float* src = xb + (size_t)(c0 + c)*TLEN + lo + c4*4;
    __builtin_amdgcn_global_load_lds(
        (const __attribute__((address_space(1))) unsigned int*)src,
        (__attribute__((address_space(3))) unsigned int*)&xs[idx*4],
        16, 0, 0);
  }
  __syncthreads();   // drains DMA (vmcnt) + sp writes (lgkm)

  // --- expand sampling params for this thread's 2x5 taps
  int   bl[2][KSZ];
  float wf[2][KSZ], wc[2][KSZ];
  bool ok = true;
  #pragma unroll
  for (int j=0;j<2;++j)
    #pragma unroll
    for (int k=0;k<KSZ;++k) {
      float2 s = sp[(j*64+tx)*KSZ + k];
      float pos = s.x, sig = s.y;
      float pf = floorf(pos), pc = ceilf(pos);
      int base = min((int)pf, TLEN-2);
      wf[j][k] = (pc - pos)*sig;     // ref quirk: pos integral -> wf=wc=0
      wc[j][k] = (pos - pf)*sig;
      int bloc = base - lo;
      bl[j][k] = bloc;
      ok = ok && (bloc >= 0) && (bloc <= XLEN-2);
    }
  if (!ok) okf = 0;
  __syncthreads();
  int fast = okf;    // block-uniform branch

  if (fast) {
    #pragma unroll 2
    for (int i=0;i<16;++i) {
      int cl = cy*16 + i;
      int cu = __builtin_amdgcn_readfirstlane(c0 + cl);
      const float* wd = wgt + (size_t)cu*(CHN*KSZ) + (size_t)cu*KSZ;  // diag
      float w0 = wd[0], w1v = wd[1], w2v = wd[2], w3 = wd[3], w4 = wd[4];
      const float* xr = xs + cl*XLEN;
      float o0, o1;
      {
        float a = 0.f;
        a = fmaf(fmaf(xr[bl[0][0]+1], wc[0][0], xr[bl[0][0]]*wf[0][0]), w0,  a);
        a = fmaf(fmaf(xr[bl[0][1]+1], wc[0][1], xr[bl[0][1]]*wf[0][1]), w1v, a);
        a = fmaf(fmaf(xr[bl[0][2]+1], wc[0][2], xr[bl[0][2]]*wf[0][2]), w2v, a);
        a = fmaf(fmaf(xr[bl[0][3]+1], wc[0][3], xr[bl[0][3]]*wf[0][3]), w3,  a);
        a = fmaf(fmaf(xr[bl[0][4]+1], wc[0][4], xr[bl[0][4]]*wf[0][4]), w4,  a);
        o0 = a;
      }
      {
        float a = 0.f;
        a = fmaf(fmaf(xr[bl[1][0]+1], wc[1][0], xr[bl[1][0]]*wf[1][0]), w0,  a);
        a = fmaf(fmaf(xr[bl[1][1]+1], wc[1][1], xr[bl[1][1]]*wf[1][1]), w1v, a);
        a = fmaf(fmaf(xr[bl[1][2]+1], wc[1][2], xr[bl[1][2]]*wf[1][2]), w2v, a);
        a = fmaf(fmaf(xr[bl[1][3]+1], wc[1][3], xr[bl[1][3]]*wf[1][3]), w3,  a);
        a = fmaf(fmaf(xr[bl[1][4]+1], wc[1][4], xr[bl[1][4]]*wf[1][4]), w4,  a);
        o1 = a;
      }
      size_t op = ((size_t)b*CHN + cu)*TLEN + t0 + tx;
      out[op]      = o0;
      out[op + 64] = o1;
    }
  } else {
    // slow path (never taken with bench weights): global gathers, same math
    for (int i=0;i<16;++i) {
      int cl = cy*16 + i;
      int cu = __builtin_amdgcn_readfirstlane(c0 + cl);
      const float* wd = wgt + (size_t)cu*(CHN*KSZ) + (size_t)cu*KSZ;
      float wk0 = wd[0], wk1 = wd[1], wk2 = wd[2], wk3 = wd[3], wk4 = wd[4];
      const float* xr = xb + (size_t)cu*TLEN + lo;   // xr[bl] == x[base]
      float o[2];
      #pragma unroll
      for (int j=0;j<2;++j) {
        float a = 0.f;
        a = fmaf(fmaf(xr[bl[j][0]+1], wc[j][0], xr[bl[j][0]]*wf[j][0]), wk0, a);
        a = fmaf(fmaf(xr[bl[j][1]+1], wc[j][1], xr[bl[j][1]]*wf[j][1]), wk1, a);
        a = fmaf(fmaf(xr[bl[j][2]+1], wc[j][2], xr[bl[j][2]]*wf[j][2]), wk2, a);
        a = fmaf(fmaf(xr[bl[j][3]+1], wc[j][3], xr[bl[j][3]]*wf[j][3]), wk3, a);
        a = fmaf(fmaf(xr[bl[j][4]+1], wc[j][4], xr[bl[j][4]]*wf[j][4]), wk4, a);
        o[j] = a;
      }
      size_t op = ((size_t)b*CHN + cu)*TLEN + t0 + tx;
      out[op]      = o[0];
      out[op + 64] = o[1];
    }
  }
}

// ---------------------------------------------------------------------------
// k2: fused rp1(conv3, 512->256)+ReLU+rp2(256->1)+bias, bf16 MFMA.
// Double-buffered 2-phase pipeline (T3 minimum recipe + T14 split):
// per ch-iter: issue next Ws DMA + next def loads (regs) -> ds_read+MFMA on
// current buffers (hides load latency) -> cvt+ds_write next Dt -> barrier.
// Grid (128 n-tiles, 2 co-halves) = 256 blocks = 1/CU, 512 thr (8 waves),
// BM=128, BN=256. LDS: Ws 2x30720 + Dt 2x20640 + Ss 1024 = 104 KB.
// Partial co-sums accumulate into outs (pre-set to b2 by kPrep) via one
// global atomicAdd per (block,n).
// ---------------------------------------------------------------------------
#define DMA_WS(dst, ch_) do {                                                  \
  _Pragma("unroll")                                                            \
  for (int r=0;r<3;++r) {                                                      \
    const char* gs = (const char*)(w1t + ((size_t)((ch_)*3+r)*256 + m0*128)*40);\
    char* ld = (char*)&Ws[dst][0] + r*10240;                                   \
    int of = tid*16;                                                           \
    __builtin_amdgcn_global_load_lds(                                          \
        (const __attribute__((address_space(1))) unsigned int*)(gs+of),        \
        (__attribute__((address_space(3))) unsigned int*)(ld+of), 16, 0, 0);   \
    if (tid < 128)                                                             \
      __builtin_amdgcn_global_load_lds(                                        \
          (const __attribute__((address_space(1))) unsigned int*)(gs+of+8192), \
          (__attribute__((address_space(3))) unsigned int*)(ld+of+8192),       \
          16, 0, 0);                                                           \
  }                                                                            \
} while(0)

#define LOAD_DT(ch_) do {                                                      \
  int ci0 = (ch_)*32;                                                          \
  const float* dpb = def + ((size_t)b*CHN + ci0 + g*8)*TLEN;                   \
  int tA = t0 - 1 + tq;                                                        \
  int tB = tA + 128;                                                           \
  int tC = tA + 256;                                                           \
  _Pragma("unroll")                                                            \
  for (int j=0;j<8;++j) ra[j] = (tA>=0 && tA<TLEN) ? dpb[(size_t)j*TLEN+tA] : 0.f;\
  _Pragma("unroll")                                                            \
  for (int j=0;j<8;++j) rb[j] = (tB<TLEN) ? dpb[(size_t)j*TLEN+tB] : 0.f;      \
  if (tq < 2) {                                                                \
    _Pragma("unroll")                                                          \
    for (int j=0;j<8;++j) rc[j] = (tC<TLEN) ? dpb[(size_t)j*TLEN+tC] : 0.f;    \
  }                                                                            \
} while(0)

#define WRITE_DT(dst) do {                                                     \
  bf16x8 v;                                                                    \
  _Pragma("unroll")                                                            \
  for (int j=0;j<8;++j) { union{bf16 h; short u;} cv;                          \
    cv.h = __float2bfloat16(ra[j]); v[j] = cv.u; }                             \
  *(bf16x8*)((char*)&Dt[dst][0] + tq*80 + g*16) = v;                           \
  _Pragma("unroll")                                                            \
  for (int j=0;j<8;++j) { union{bf16 h; short u;} cv;                          \
    cv.h = __float2bfloat16(rb[j]); v[j] = cv.u; }                             \
  *(bf16x8*)((char*)&Dt[dst][0] + (tq+128)*80 + g*16) = v;                     \
  if (tq < 2) {                                                                \
    _Pragma("unroll")                                                          \
    for (int j=0;j<8;++j) { union{bf16 h; short u;} cv;                        \
      cv.h = __float2bfloat16(rc[j]); v[j] = cv.u; }                           \
    *(bf16x8*)((char*)&Dt[dst][0] + (tq+256)*80 + g*16) = v;                   \
  }                                                                            \
} while(0)

#define COMPUTE(cur) do {                                                      \
  _Pragma("unroll")                                                            \
  for (int r=0;r<3;++r) {                                                      \
    bf16x8 af[4], bfr[4];                                                      \
    _Pragma("unroll")                                                          \
    for (int mt=0;mt<4;++mt)                                                   \
      af[mt] = *(const bf16x8*)&Ws[cur][(size_t)(r*128 + wM*64 + mt*16 + ln15)*40 + quad*8];\
    _Pragma("unroll")                                                          \
    for (int nt=0;nt<4;++nt)                                                   \
      bfr[nt] = *(const bf16x8*)&Dt[cur][(size_t)(wN*64 + nt*16 + ln15 + r)*40 + quad*8];\
    _Pragma("unroll")                                                          \
    for (int mt=0;mt<4;++mt)                                                   \
      _Pragma("unroll")                                                        \
      for (int nt=0;nt<4;++nt)                                                 \
        acc[mt][nt] = __builtin_amdgcn_mfma_f32_16x16x32_bf16(                 \
            af[mt], bfr[nt], acc[mt][nt], 0, 0, 0);                            \
  }                                                                            \
} while(0)

__global__ __launch_bounds__(512, 2) void k2(const float* __restrict__ def,
    const bf16* __restrict__ w1t, const float* __restrict__ b1,
    const float* __restrict__ w2, float* __restrict__ outs)
{
  int n0 = blockIdx.x*256;         // 128 n-tiles (BN=256, divides TLEN)
  int m0 = blockIdx.y;             // 0,1: co half
  int b  = n0 / TLEN;
  int t0 = n0 % TLEN;
  int tid  = threadIdx.x;          // 0..511
  int lane = tid & 63;
  int wave = tid >> 6;             // 0..7
  int wM   = wave & 1;             // 64-row co group
  int wN   = wave >> 1;            // 0..3: 64-col n group
  int ln15 = lane & 15, quad = lane >> 4;

  __shared__ bf16 Ws[2][3*128*40]; // 61,440 B
  __shared__ bf16 Dt[2][258*40];   // 41,280 B
  __shared__ float Ss[256];

  // Dt staging geometry: thread -> (ci-octet g, t-rows tq, tq+128[, tq+256])
  int g  = tid >> 7;               // 0..3
  int tq = tid & 127;

  f32x4 acc[4][4];
  #pragma unroll
  for (int i=0;i<4;++i)
    #pragma unroll
    for (int j=0;j<4;++j) acc[i][j] = (f32x4){0.f,0.f,0.f,0.f};

  float ra[8], rb[8], rc[8];
  #pragma unroll
  for (int j=0;j<8;++j) rc[j] = 0.f;

  // prologue: stage ch=0 into buffer 0
  DMA_WS(0, 0);
  LOAD_DT(0);
  WRITE_DT(0);
  __syncthreads();                 // drains DMA (vmcnt) + lds writes

  for (int ch=0; ch<16; ++ch) {
    int cur = ch & 1;
    int nxt = cur ^ 1;
    if (ch < 15) {                 // issue next chunk early (uniform branch)
      DMA_WS(nxt, ch+1);
      LOAD_DT(ch+1);
    }
    COMPUTE(cur);                  // ds_read + MFMA hide the in-flight loads
    if (ch < 15)
      WRITE_DT(nxt);               // compiler waits loads just before cvt
    __syncthreads();               // one barrier per iter; drains DMA too
  }

  // epilogue: strength[n] += sum_{co in half} relu(H[co][n]+b1[co]) * w2[co]
  float part[4] = {0.f,0.f,0.f,0.f};
  #pragma unroll
  for (int mt=0;mt<4;++mt) {
    #pragma unroll
    for (int rr=0;rr<4;++rr) {
      int row = m0*128 + wM*64 + mt*16 + quad*4 + rr;
      float bias = b1[row];
      float wv   = w2[row];
      #pragma unroll
      for (int nt=0;nt<4;++nt) {
        float h = acc[mt][nt][rr] + bias;
        h = fmaxf(h, 0.f);
        part[nt] = fmaf(h, wv, part[nt]);
      }
    }
  }
  if (tid < 256) Ss[tid] = 0.f;
  __syncthreads();
  #pragma unroll
  for (int nt=0;nt<4;++nt)
    atomicAdd(&Ss[wN*64 + nt*16 + ln15], part[nt]);
  __syncthreads();
  if (tid < 256)
    atomicAdd(&outs[n0 + tid], Ss[tid]);
}

extern "C" void kernel_launch(void* const* d_in, const int* in_sizes, int n_in,
                              void* d_out, int out_size, void* d_ws, size_t ws_size,
                              hipStream_t stream) {
  const float* x  = (const float*)d_in[0];
  const float* ow = (const float*)d_in[1];
  const float* ob = (const float*)d_in[2];
  const float* mw = (const float*)d_in[3];
  const float* mb = (const float*)d_in[4];
  const float* wg = (const float*)d_in[5];
  const float* w1 = (const float*)d_in[6];
  const float* b1 = (const float*)d_in[7];
  const float* w2 = (const float*)d_in[8];
  const float* b2 = (const float*)d_in[9];

  float* out_def = (float*)d_out;
  float* out_str = out_def + (size_t)BATCH*CHN*TLEN;

  float2* samp = (float2*)d_ws;                                  // 1.31 MB
  bf16*   w1t  = (bf16*)((char*)d_ws + SAMP_BYTES);              // 983 KB
  float*  wpk  = (float*)((char*)d_ws + SAMP_BYTES + W1T_BYTES); // 64 KB

  kPrep<<<dim3(1920+64+128), 256, 0, stream>>>(w1, w1t, ow, mw, wpk, out_str, b2);
  kS   <<<dim3(TLEN/64, BATCH), dim3(64,8), 0, stream>>>(x, wpk, ob, mb, samp);
  kDf  <<<dim3(TLEN/BT, CHN/64, BATCH), dim3(64,4), 0, stream>>>(x, wg, samp, out_def);
  k2   <<<dim3(BATCH*TLEN/256, 2), 512, 0, stream>>>(out_def, w1t, b1, w2, out_str);
}

// Round 4
// 244.600 us; speedup vs baseline: 1.1445x; 1.1445x over previous
//
#include <hip/hip_runtime.h>
#include <hip/hip_bf16.h>

#define CHN 512
#define TLEN 2048
#define KSZ 5
#define BATCH 16

typedef __hip_bfloat16 bf16;
typedef short bf16x8 __attribute__((ext_vector_type(8)));   // 8 bf16 (4 VGPRs)
typedef float f32x4  __attribute__((ext_vector_type(4)));

// W tile row stride: 44 bf16 (32 data + 12 pad) = 88 B = 22 words.
// gcd(22,32)=2 -> 16-lane fragment reads get distinct start banks (was 40
// elems = 20 words, gcd 4 -> 8-way span pileup, 3.17M conflict cycles).
#define WST 44

// ws layout:
//   samp : float2[B*T*5]  (pos, sig)       = 1,310,720 B
//   w1t  : bf16 [16][3][256][WST]          = 1,081,344 B   (pre-tiled W1)
//   wpk  : float[512][32]                  =    65,536 B   (packed ow+mw)
#define SAMP_BYTES (BATCH*TLEN*KSZ*8)
#define W1T_ELEMS  (16*3*256*WST)
#define W1T_BYTES  (W1T_ELEMS*2)

// ---------------------------------------------------------------------------
// kPrep: fused kP (w1 retile, 2112 blocks) + kW (ow/mw pack, 64 blocks) +
//        kZ (outs = b2, 128 blocks). One dispatch instead of three.
// ---------------------------------------------------------------------------
__global__ __launch_bounds__(256) void kPrep(const float* __restrict__ w1,
    bf16* __restrict__ w1t, const float* __restrict__ ow,
    const float* __restrict__ mw, float* __restrict__ wpk,
    float* __restrict__ outs, const float* __restrict__ b2p)
{
  int bx = blockIdx.x;
  int tidl = threadIdx.x;
  if (bx < W1T_ELEMS/256) {
    // kP: w1 fp32 [co][ci][r] -> w1t bf16 [ch][r][co][WST]
    int idx  = bx*256 + tidl;                    // < 540672
    int c40  = idx % WST;
    int rest = idx / WST;
    int co   = rest & 255;
    int rr   = rest >> 8;          // ch*3 + r
    int r    = rr % 3;
    int ch   = rr / 3;
    float v = 0.f;
    if (c40 < 32) v = w1[(size_t)co*(CHN*3) + (ch*32 + c40)*3 + r];
    w1t[idx] = __float2bfloat16(v);
  } else if (bx < W1T_ELEMS/256 + 64) {
    // kW: pack ow/mw -> wpk[c][32]
    int idx = (bx - W1T_ELEMS/256)*256 + tidl;   // < 16384
    int j = idx & 31, c = idx >> 5;
    float v = 0.f;
    if (j < 15)      { int o = j/3,  d = j - o*3;  v = ow[o*(CHN*3) + c*3 + d]; }
    else if (j < 30) { int jj = j-15; int o = jj/3, d = jj - o*3;
                       v = mw[o*(CHN*3) + c*3 + d]; }
    wpk[idx] = v;
  } else {
    // kZ: outs = b2 (k2 blocks atomically accumulate on top)
    outs[(bx - W1T_ELEMS/256 - 64)*256 + tidl] = b2p[0];
  }
}

// ---------------------------------------------------------------------------
// kS: offset conv (out 0..4) + modulator conv (+sigmoid) -> sampling params.
// grid (TLEN/64, B), block (64 t, 8 cg). Each thread reduces 64 channels.
// samp[b,t,k] = (pos, sig); kDf re-derives base/wf/wc (bitwise-identical).
// ---------------------------------------------------------------------------
__global__ __launch_bounds__(512) void kS(const float* __restrict__ x,
    const float* __restrict__ wpk, const float* __restrict__ ob,
    const float* __restrict__ mb, float2* __restrict__ samp)
{
  int b  = blockIdx.y;
  int t0 = blockIdx.x*64;
  int tx = threadIdx.x;
  int cg = threadIdx.y;            // 0..7 (wave-uniform: wave = one tx row)
  int t  = t0 + tx;

  __shared__ float red[8][64][10];

  float acc[10];
  #pragma unroll
  for (int i=0;i<10;++i) acc[i]=0.f;
  const float* xb = x + (size_t)b*CHN*TLEN;
  int c0 = cg*64;
  #pragma unroll 4
  for (int c=c0;c<c0+64;++c) {
    int cu = __builtin_amdgcn_readfirstlane(c);
    const float* wp = wpk + cu*32;             // scalar -> s_load_dwordx8
    const float* xr = xb + (size_t)cu*TLEN;
    float xm = (t>0)      ? xr[t-1] : 0.f;
    float xc = xr[t];
    float xp = (t<TLEN-1) ? xr[t+1] : 0.f;
    #pragma unroll
    for (int o=0;o<5;++o) {
      acc[o]   = fmaf(xm, wp[o*3+0],    acc[o]);
      acc[o]   = fmaf(xc, wp[o*3+1],    acc[o]);
      acc[o]   = fmaf(xp, wp[o*3+2],    acc[o]);
      acc[5+o] = fmaf(xm, wp[15+o*3+0], acc[5+o]);
      acc[5+o] = fmaf(xc, wp[15+o*3+1], acc[5+o]);
      acc[5+o] = fmaf(xp, wp[15+o*3+2], acc[5+o]);
    }
  }
  #pragma unroll
  for (int i=0;i<10;++i) red[cg][tx][i] = acc[i];
  __syncthreads();
  for (int s=4;s>0;s>>=1) {
    if (cg < s) {
      #pragma unroll
      for (int i=0;i<10;++i) red[cg][tx][i] += red[cg+s][tx][i];
    }
    __syncthreads();
  }
  if (cg==0) {
    #pragma unroll
    for (int k=0;k<KSZ;++k) {
      float off = red[0][tx][k]   + ob[k];
      float mv  = red[0][tx][5+k] + mb[k];
      float sig = 1.f/(1.f + expf(-mv));
      float pos = (float)(t + k - 2) + off;
      pos = fminf(fmaxf(pos, 0.f), (float)(TLEN-1));
      samp[((size_t)b*TLEN + t)*KSZ + k] = make_float2(pos, sig);
    }
  }
}

// ---------------------------------------------------------------------------
// kDf: deformable sampling w/ diagonal weight — LDS-tiled.
// grid (T/128, C/64, B), block (64,4). Block stages x[c0..c0+63][lo..lo+159]
// into LDS via global_load_lds DMA (coalesced), then serves all gathers from
// LDS. Thread owns t = t0 + j*64 + tx (lane-consecutive) x 16 c-rows.
// Block-uniform fallback to global gathers if any base escapes the halo.
// ---------------------------------------------------------------------------
#define BT   128
#define HALO 16
#define XLEN 160   // BT + 2*HALO

__global__ __launch_bounds__(256) void kDf(const float* __restrict__ x,
    const float* __restrict__ wgt, const float2* __restrict__ sampg,
    float* __restrict__ out)
{
  int b  = blockIdx.z;
  int c0 = blockIdx.y*64;
  int t0 = blockIdx.x*BT;
  int tx = threadIdx.x, cy = threadIdx.y;
  int tid = cy*64 + tx;

  __shared__ float  xs[64*XLEN];    // 40,960 B
  __shared__ float2 sp[BT*KSZ];     //  5,120 B
  __shared__ int okf;

  int lo = min(max(t0 - HALO, 0), TLEN - XLEN);   // window always in-bounds

  if (tid == 0) okf = 1;
  for (int i = tid; i < BT*KSZ; i += 256)
    sp[i] = sampg[((size_t)b*TLEN + t0)*KSZ + i];

  // --- DMA x tile: 64 rows x 160 floats = 2560 float4 chunks, 10/thread.
  const float* xb = x + (size_t)b*CHN*TLEN;
  #pragma unroll
  for (int it = 0; it < 10; ++it) {
    int idx = tid + it*256;
    int c  = idx / 40;             // local c row
    int c4 = idx - c*40;           // float4 within row
    const float* src = xb + (size_t)(c0 + c)*TLEN + lo + c4*4;
    __builtin_amdgcn_global_load_lds(
        (const __attribute__((address_space(1))) unsigned int*)src,
        (__attribute__((address_space(3))) unsigned int*)&xs[idx*4],
        16, 0, 0);
  }
  __syncthreads();   // drains DMA (vmcnt) + sp writes (lgkm)

  // --- expand sampling params for this thread's 2x5 taps
  int   bl[2][KSZ];
  float wf[2][KSZ], wc[2][KSZ];
  bool ok = true;
  #pragma unroll
  for (int j=0;j<2;++j)
    #pragma unroll
    for (int k=0;k<KSZ;++k) {
      float2 s = sp[(j*64+tx)*KSZ + k];
      float pos = s.x, sig = s.y;
      float pf = floorf(pos), pc = ceilf(pos);
      int base = min((int)pf, TLEN-2);
      wf[j][k] = (pc - pos)*sig;     // ref quirk: pos integral -> wf=wc=0
      wc[j][k] = (pos - pf)*sig;
      int bloc = base - lo;
      bl[j][k] = bloc;
      ok = ok && (bloc >= 0) && (bloc <= XLEN-2);
    }
  if (!ok) okf = 0;
  __syncthreads();
  int fast = okf;    // block-uniform branch

  if (fast) {
    #pragma unroll 2
    for (int i=0;i<16;++i) {
      int cl = cy*16 + i;
      int cu = __builtin_amdgcn_readfirstlane(c0 + cl);
      const float* wd = wgt + (size_t)cu*(CHN*KSZ) + (size_t)cu*KSZ;  // diag
      float w0 = wd[0], w1v = wd[1], w2v = wd[2], w3 = wd[3], w4 = wd[4];
      const float* xr = xs + cl*XLEN;
      float o0, o1;
      {
        float a = 0.f;
        a = fmaf(fmaf(xr[bl[0][0]+1], wc[0][0], xr[bl[0][0]]*wf[0][0]), w0,  a);
        a = fmaf(fmaf(xr[bl[0][1]+1], wc[0][1], xr[bl[0][1]]*wf[0][1]), w1v, a);
        a = fmaf(fmaf(xr[bl[0][2]+1], wc[0][2], xr[bl[0][2]]*wf[0][2]), w2v, a);
        a = fmaf(fmaf(xr[bl[0][3]+1], wc[0][3], xr[bl[0][3]]*wf[0][3]), w3,  a);
        a = fmaf(fmaf(xr[bl[0][4]+1], wc[0][4], xr[bl[0][4]]*wf[0][4]), w4,  a);
        o0 = a;
      }
      {
        float a = 0.f;
        a = fmaf(fmaf(xr[bl[1][0]+1], wc[1][0], xr[bl[1][0]]*wf[1][0]), w0,  a);
        a = fmaf(fmaf(xr[bl[1][1]+1], wc[1][1], xr[bl[1][1]]*wf[1][1]), w1v, a);
        a = fmaf(fmaf(xr[bl[1][2]+1], wc[1][2], xr[bl[1][2]]*wf[1][2]), w2v, a);
        a = fmaf(fmaf(xr[bl[1][3]+1], wc[1][3], xr[bl[1][3]]*wf[1][3]), w3,  a);
        a = fmaf(fmaf(xr[bl[1][4]+1], wc[1][4], xr[bl[1][4]]*wf[1][4]), w4,  a);
        o1 = a;
      }
      size_t op = ((size_t)b*CHN + cu)*TLEN + t0 + tx;
      out[op]      = o0;
      out[op + 64] = o1;
    }
  } else {
    // slow path (never taken with bench weights): global gathers, same math
    for (int i=0;i<16;++i) {
      int cl = cy*16 + i;
      int cu = __builtin_amdgcn_readfirstlane(c0 + cl);
      const float* wd = wgt + (size_t)cu*(CHN*KSZ) + (size_t)cu*KSZ;
      float wk0 = wd[0], wk1 = wd[1], wk2 = wd[2], wk3 = wd[3], wk4 = wd[4];
      const float* xr = xb + (size_t)cu*TLEN + lo;   // xr[bl] == x[base]
      float o[2];
      #pragma unroll
      for (int j=0;j<2;++j) {
        float a = 0.f;
        a = fmaf(fmaf(xr[bl[j][0]+1], wc[j][0], xr[bl[j][0]]*wf[j][0]), wk0, a);
        a = fmaf(fmaf(xr[bl[j][1]+1], wc[j][1], xr[bl[j][1]]*wf[j][1]), wk1, a);
        a = fmaf(fmaf(xr[bl[j][2]+1], wc[j][2], xr[bl[j][2]]*wf[j][2]), wk2, a);
        a = fmaf(fmaf(xr[bl[j][3]+1], wc[j][3], xr[bl[j][3]]*wf[j][3]), wk3, a);
        a = fmaf(fmaf(xr[bl[j][4]+1], wc[j][4], xr[bl[j][4]]*wf[j][4]), wk4, a);
        o[j] = a;
      }
      size_t op = ((size_t)b*CHN + cu)*TLEN + t0 + tx;
      out[op]      = o[0];
      out[op + 64] = o[1];
    }
  }
}

// ---------------------------------------------------------------------------
// k2: fused rp1(conv3, 512->256)+ReLU+rp2(256->1)+bias, bf16 MFMA.
// R2 structure (measured 59us: 2 blocks/CU, inter-block phase overlap) with
// WST=44 row stride -> conflict-free fragment ds_reads.
// Grid (256 n-tiles, 2 co-halves), 256 thr (4 waves), BM=128, BN=128.
// Dt staged as bf16x8 per thread (conflict-free ds_write_b128). Partial
// co-sums accumulate into outs (pre-set to b2 by kPrep) via one global
// atomicAdd per (block,n).
// ---------------------------------------------------------------------------
__global__ __launch_bounds__(256, 2) void k2(const float* __restrict__ def,
    const bf16* __restrict__ w1t, const float* __restrict__ b1,
    const float* __restrict__ w2, float* __restrict__ outs)
{
  int n0 = blockIdx.x*128;
  int m0 = blockIdx.y;             // 0,1: co half
  int b  = n0 / TLEN;
  int t0 = n0 % TLEN;
  int tid  = threadIdx.x;          // 0..255
  int lane = tid & 63;
  int wave = tid >> 6;             // 0..3
  int wM   = wave & 1;             // 64-row co group
  int wN   = wave >> 1;            // 64-col n group
  int ln15 = lane & 15, quad = lane >> 4;

  __shared__ bf16 Ws[3*128*WST];   // 33,792 B
  __shared__ bf16 Dt[130*WST];     // 11,440 B
  __shared__ float Ss[128];

  f32x4 acc[4][4];
  #pragma unroll
  for (int i=0;i<4;++i)
    #pragma unroll
    for (int j=0;j<4;++j) acc[i][j] = (f32x4){0.f,0.f,0.f,0.f};

  for (int ch=0; ch<16; ++ch) {
    // --- async DMA: Ws <- w1t chunk, 3 spans of 11264 B (co half m0)
    #pragma unroll
    for (int r=0;r<3;++r) {
      const char* gs = (const char*)(w1t + ((size_t)(ch*3+r)*256 + m0*128)*WST);
      char* ld = (char*)Ws + r*(128*WST*2);
      for (int of = tid*16; of < 128*WST*2; of += 4096) {
        __builtin_amdgcn_global_load_lds(
            (const __attribute__((address_space(1))) unsigned int*)(gs + of),
            (__attribute__((address_space(3))) unsigned int*)(ld + of),
            16, 0, 0);
      }
    }
    // --- Dt[tt][ci] <- def[ci0+ci][t0-1+tt]: thread packs 8 ci for one tt,
    // single ds_write_b128 (conflict-free). 520 slots = 130 tt x 4 ci-octets.
    int ci0 = ch*32;
    for (int s = tid; s < 520; s += 256) {
      int g  = s / 130;            // ci octet 0..3
      int tt = s - g*130;
      int t  = t0 - 1 + tt;
      bf16x8 v = (bf16x8){0,0,0,0,0,0,0,0};
      if (t >= 0 && t < TLEN) {
        const float* dp = def + ((size_t)b*CHN + ci0 + g*8)*TLEN + t;
        #pragma unroll
        for (int j=0;j<8;++j) {
          union { bf16 h; short u; } cv;
          cv.h = __float2bfloat16(dp[(size_t)j*TLEN]);
          v[j] = cv.u;
        }
      }
      *(bf16x8*)((char*)Dt + tt*(WST*2) + g*16) = v;
    }
    __syncthreads();   // drains DMA (vmcnt) + lds writes (lgkm)

    #pragma unroll
    for (int r=0;r<3;++r) {
      bf16x8 af[4], bfr[4];
      #pragma unroll
      for (int mt=0;mt<4;++mt)
        af[mt] = *(const bf16x8*)&Ws[(size_t)(r*128 + wM*64 + mt*16 + ln15)*WST + quad*8];
      #pragma unroll
      for (int nt=0;nt<4;++nt)
        bfr[nt] = *(const bf16x8*)&Dt[(size_t)(wN*64 + nt*16 + ln15 + r)*WST + quad*8];
      #pragma unroll
      for (int mt=0;mt<4;++mt)
        #pragma unroll
        for (int nt=0;nt<4;++nt)
          acc[mt][nt] = __builtin_amdgcn_mfma_f32_16x16x32_bf16(
              af[mt], bfr[nt], acc[mt][nt], 0, 0, 0);
    }
    __syncthreads();   // protect Ws/Dt before next chunk overwrites
  }

  // epilogue: strength[n] += sum_{co in half} relu(H[co][n]+b1[co]) * w2[co]
  float part[4] = {0.f,0.f,0.f,0.f};
  #pragma unroll
  for (int mt=0;mt<4;++mt) {
    #pragma unroll
    for (int rr=0;rr<4;++rr) {
      int row = m0*128 + wM*64 + mt*16 + quad*4 + rr;
      float bias = b1[row];
      float wv   = w2[row];
      #pragma unroll
      for (int nt=0;nt<4;++nt) {
        float h = acc[mt][nt][rr] + bias;
        h = fmaxf(h, 0.f);
        part[nt] = fmaf(h, wv, part[nt]);
      }
    }
  }
  if (tid < 128) Ss[tid] = 0.f;
  __syncthreads();
  #pragma unroll
  for (int nt=0;nt<4;++nt)
    atomicAdd(&Ss[wN*64 + nt*16 + ln15], part[nt]);
  __syncthreads();
  if (tid < 128)
    atomicAdd(&outs[n0 + tid], Ss[tid]);
}

extern "C" void kernel_launch(void* const* d_in, const int* in_sizes, int n_in,
                              void* d_out, int out_size, void* d_ws, size_t ws_size,
                              hipStream_t stream) {
  const float* x  = (const float*)d_in[0];
  const float* ow = (const float*)d_in[1];
  const float* ob = (const float*)d_in[2];
  const float* mw = (const float*)d_in[3];
  const float* mb = (const float*)d_in[4];
  const float* wg = (const float*)d_in[5];
  const float* w1 = (const float*)d_in[6];
  const float* b1 = (const float*)d_in[7];
  const float* w2 = (const float*)d_in[8];
  const float* b2 = (const float*)d_in[9];

  float* out_def = (float*)d_out;
  float* out_str = out_def + (size_t)BATCH*CHN*TLEN;

  float2* samp = (float2*)d_ws;                                  // 1.31 MB
  bf16*   w1t  = (bf16*)((char*)d_ws + SAMP_BYTES);              // 1.08 MB
  float*  wpk  = (float*)((char*)d_ws + SAMP_BYTES + W1T_BYTES); // 64 KB

  kPrep<<<dim3(W1T_ELEMS/256 + 64 + 128), 256, 0, stream>>>(
      w1, w1t, ow, mw, wpk, out_str, b2);
  kS   <<<dim3(TLEN/64, BATCH), dim3(64,8), 0, stream>>>(x, wpk, ob, mb, samp);
  kDf  <<<dim3(TLEN/BT, CHN/64, BATCH), dim3(64,4), 0, stream>>>(x, wg, samp, out_def);
  k2   <<<dim3(BATCH*TLEN/128, 2), 256, 0, stream>>>(out_def, w1t, b1, w2, out_str);
}

// Round 5
// 228.979 us; speedup vs baseline: 1.2226x; 1.0682x over previous
//
#include <hip/hip_runtime.h>
#include <hip/hip_bf16.h>

#define CHN 512
#define TLEN 2048
#define KSZ 5
#define BATCH 16

typedef __hip_bfloat16 bf16;
typedef short bf16x8 __attribute__((ext_vector_type(8)));   // 8 bf16 (4 VGPRs)
typedef float f32x4  __attribute__((ext_vector_type(4)));

// ws layout:
//   samp : float2[B*T*5]  (pos, sig)       = 1,310,720 B
//   w1t  : bf16 [16][4][3][64][40]         =   983,040 B   (pre-tiled W1)
//   wpk  : float[512][32]                  =    65,536 B   (packed ow+mw)
#define SAMP_BYTES (BATCH*TLEN*KSZ*8)
#define W1T_ELEMS  (16*4*3*64*40)
#define W1T_BYTES  (W1T_ELEMS*2)

// ---------------------------------------------------------------------------
// kPrep: fused kP (w1 retile, 1920 blocks) + kW (ow/mw pack, 64 blocks) +
//        kZ (outs = b2, 128 blocks). One dispatch instead of three.
// ---------------------------------------------------------------------------
__global__ __launch_bounds__(256) void kPrep(const float* __restrict__ w1,
    bf16* __restrict__ w1t, const float* __restrict__ ow,
    const float* __restrict__ mw, float* __restrict__ wpk,
    float* __restrict__ outs, const float* __restrict__ b2p)
{
  int bx = blockIdx.x;
  int tidl = threadIdx.x;
  if (bx < W1T_ELEMS/256) {
    // kP: w1 fp32 [co][ci][r] -> w1t bf16 [ch][q][r][row][40], co = q*64+row
    int idx  = bx*256 + tidl;                    // < 491520
    int c40  = idx % 40;
    int rest = idx / 40;
    int row  = rest & 63;
    int rr   = rest >> 6;          // (ch*4+q)*3 + r
    int r    = rr % 3;
    int cq   = rr / 3;             // ch*4 + q
    int q    = cq & 3;
    int ch   = cq >> 2;
    int co   = q*64 + row;
    float v = 0.f;
    if (c40 < 32) v = w1[(size_t)co*(CHN*3) + (ch*32 + c40)*3 + r];
    w1t[idx] = __float2bfloat16(v);
  } else if (bx < W1T_ELEMS/256 + 64) {
    // kW: pack ow/mw -> wpk[c][32]
    int idx = (bx - W1T_ELEMS/256)*256 + tidl;   // < 16384
    int j = idx & 31, c = idx >> 5;
    float v = 0.f;
    if (j < 15)      { int o = j/3,  d = j - o*3;  v = ow[o*(CHN*3) + c*3 + d]; }
    else if (j < 30) { int jj = j-15; int o = jj/3, d = jj - o*3;
                       v = mw[o*(CHN*3) + c*3 + d]; }
    wpk[idx] = v;
  } else {
    // kZ: outs = b2 (k2 blocks atomically accumulate on top)
    outs[(bx - W1T_ELEMS/256 - 64)*256 + tidl] = b2p[0];
  }
}

// ---------------------------------------------------------------------------
// kS: offset conv (out 0..4) + modulator conv (+sigmoid) -> sampling params.
// grid (TLEN/64, B), block (64 t, 8 cg). Each thread reduces 64 channels.
// samp[b,t,k] = (pos, sig); kDf re-derives base/wf/wc (bitwise-identical).
// ---------------------------------------------------------------------------
__global__ __launch_bounds__(512) void kS(const float* __restrict__ x,
    const float* __restrict__ wpk, const float* __restrict__ ob,
    const float* __restrict__ mb, float2* __restrict__ samp)
{
  int b  = blockIdx.y;
  int t0 = blockIdx.x*64;
  int tx = threadIdx.x;
  int cg = threadIdx.y;            // 0..7 (wave-uniform: wave = one tx row)
  int t  = t0 + tx;

  __shared__ float red[8][64][10];

  float acc[10];
  #pragma unroll
  for (int i=0;i<10;++i) acc[i]=0.f;
  const float* xb = x + (size_t)b*CHN*TLEN;
  int c0 = cg*64;
  #pragma unroll 4
  for (int c=c0;c<c0+64;++c) {
    int cu = __builtin_amdgcn_readfirstlane(c);
    const float* wp = wpk + cu*32;             // scalar -> s_load_dwordx8
    const float* xr = xb + (size_t)cu*TLEN;
    float xm = (t>0)      ? xr[t-1] : 0.f;
    float xc = xr[t];
    float xp = (t<TLEN-1) ? xr[t+1] : 0.f;
    #pragma unroll
    for (int o=0;o<5;++o) {
      acc[o]   = fmaf(xm, wp[o*3+0],    acc[o]);
      acc[o]   = fmaf(xc, wp[o*3+1],    acc[o]);
      acc[o]   = fmaf(xp, wp[o*3+2],    acc[o]);
      acc[5+o] = fmaf(xm, wp[15+o*3+0], acc[5+o]);
      acc[5+o] = fmaf(xc, wp[15+o*3+1], acc[5+o]);
      acc[5+o] = fmaf(xp, wp[15+o*3+2], acc[5+o]);
    }
  }
  #pragma unroll
  for (int i=0;i<10;++i) red[cg][tx][i] = acc[i];
  __syncthreads();
  for (int s=4;s>0;s>>=1) {
    if (cg < s) {
      #pragma unroll
      for (int i=0;i<10;++i) red[cg][tx][i] += red[cg+s][tx][i];
    }
    __syncthreads();
  }
  if (cg==0) {
    #pragma unroll
    for (int k=0;k<KSZ;++k) {
      float off = red[0][tx][k]   + ob[k];
      float mv  = red[0][tx][5+k] + mb[k];
      float sig = 1.f/(1.f + expf(-mv));
      float pos = (float)(t + k - 2) + off;
      pos = fminf(fmaxf(pos, 0.f), (float)(TLEN-1));
      samp[((size_t)b*TLEN + t)*KSZ + k] = make_float2(pos, sig);
    }
  }
}

// ---------------------------------------------------------------------------
// kDf: deformable sampling w/ diagonal weight — LDS-tiled.
// grid (T/128, C/64, B), block (64,4). Block stages x[c0..c0+63][lo..lo+159]
// into LDS via global_load_lds DMA (coalesced), then serves all gathers from
// LDS. Thread owns t = t0 + j*64 + tx (lane-consecutive) x 16 c-rows.
// Block-uniform fallback to global gathers if any base escapes the halo.
// ---------------------------------------------------------------------------
#define BT   128
#define HALO 16
#define XLEN 160   // BT + 2*HALO

__global__ __launch_bounds__(256) void kDf(const float* __restrict__ x,
    const float* __restrict__ wgt, const float2* __restrict__ sampg,
    float* __restrict__ out)
{
  int b  = blockIdx.z;
  int c0 = blockIdx.y*64;
  int t0 = blockIdx.x*BT;
  int tx = threadIdx.x, cy = threadIdx.y;
  int tid = cy*64 + tx;

  __shared__ float  xs[64*XLEN];    // 40,960 B
  __shared__ float2 sp[BT*KSZ];     //  5,120 B
  __shared__ int okf;

  int lo = min(max(t0 - HALO, 0), TLEN - XLEN);   // window always in-bounds

  if (tid == 0) okf = 1;
  for (int i = tid; i < BT*KSZ; i += 256)
    sp[i] = sampg[((size_t)b*TLEN + t0)*KSZ + i];

  // --- DMA x tile: 64 rows x 160 floats = 2560 float4 chunks, 10/thread.
  const float* xb = x + (size_t)b*CHN*TLEN;
  #pragma unroll
  for (int it = 0; it < 10; ++it) {
    int idx = tid + it*256;
    int c  = idx / 40;             // local c row
    int c4 = idx - c*40;           // float4 within row
    const float* src = xb + (size_t)(c0 + c)*TLEN + lo + c4*4;
    __builtin_amdgcn_global_load_lds(
        (const __attribute__((address_space(1))) unsigned int*)src,
        (__attribute__((address_space(3))) unsigned int*)&xs[idx*4],
        16, 0, 0);
  }
  __syncthreads();   // drains DMA (vmcnt) + sp writes (lgkm)

  // --- expand sampling params for this thread's 2x5 taps
  int   bl[2][KSZ];
  float wf[2][KSZ], wc[2][KSZ];
  bool ok = true;
  #pragma unroll
  for (int j=0;j<2;++j)
    #pragma unroll
    for (int k=0;k<KSZ;++k) {
      float2 s = sp[(j*64+tx)*KSZ + k];
      float pos = s.x, sig = s.y;
      float pf = floorf(pos), pc = ceilf(pos);
      int base = min((int)pf, TLEN-2);
      wf[j][k] = (pc - pos)*sig;     // ref quirk: pos integral -> wf=wc=0
      wc[j][k] = (pos - pf)*sig;
      int bloc = base - lo;
      bl[j][k] = bloc;
      ok = ok && (bloc >= 0) && (bloc <= XLEN-2);
    }
  if (!ok) okf = 0;
  __syncthreads();
  int fast = okf;    // block-uniform branch

  if (fast) {
    #pragma unroll 2
    for (int i=0;i<16;++i) {
      int cl = cy*16 + i;
      int cu = __builtin_amdgcn_readfirstlane(c0 + cl);
      const float* wd = wgt + (size_t)cu*(CHN*KSZ) + (size_t)cu*KSZ;  // diag
      float w0 = wd[0], w1v = wd[1], w2v = wd[2], w3 = wd[3], w4 = wd[4];
      const float* xr = xs + cl*XLEN;
      float o0, o1;
      {
        float a = 0.f;
        a = fmaf(fmaf(xr[bl[0][0]+1], wc[0][0], xr[bl[0][0]]*wf[0][0]), w0,  a);
        a = fmaf(fmaf(xr[bl[0][1]+1], wc[0][1], xr[bl[0][1]]*wf[0][1]), w1v, a);
        a = fmaf(fmaf(xr[bl[0][2]+1], wc[0][2], xr[bl[0][2]]*wf[0][2]), w2v, a);
        a = fmaf(fmaf(xr[bl[0][3]+1], wc[0][3], xr[bl[0][3]]*wf[0][3]), w3,  a);
        a = fmaf(fmaf(xr[bl[0][4]+1], wc[0][4], xr[bl[0][4]]*wf[0][4]), w4,  a);
        o0 = a;
      }
      {
        float a = 0.f;
        a = fmaf(fmaf(xr[bl[1][0]+1], wc[1][0], xr[bl[1][0]]*wf[1][0]), w0,  a);
        a = fmaf(fmaf(xr[bl[1][1]+1], wc[1][1], xr[bl[1][1]]*wf[1][1]), w1v, a);
        a = fmaf(fmaf(xr[bl[1][2]+1], wc[1][2], xr[bl[1][2]]*wf[1][2]), w2v, a);
        a = fmaf(fmaf(xr[bl[1][3]+1], wc[1][3], xr[bl[1][3]]*wf[1][3]), w3,  a);
        a = fmaf(fmaf(xr[bl[1][4]+1], wc[1][4], xr[bl[1][4]]*wf[1][4]), w4,  a);
        o1 = a;
      }
      size_t op = ((size_t)b*CHN + cu)*TLEN + t0 + tx;
      out[op]      = o0;
      out[op + 64] = o1;
    }
  } else {
    // slow path (never taken with bench weights): global gathers, same math
    for (int i=0;i<16;++i) {
      int cl = cy*16 + i;
      int cu = __builtin_amdgcn_readfirstlane(c0 + cl);
      const float* wd = wgt + (size_t)cu*(CHN*KSZ) + (size_t)cu*KSZ;
      float wk0 = wd[0], wk1 = wd[1], wk2 = wd[2], wk3 = wd[3], wk4 = wd[4];
      const float* xr = xb + (size_t)cu*TLEN + lo;   // xr[bl] == x[base]
      float o[2];
      #pragma unroll
      for (int j=0;j<2;++j) {
        float a = 0.f;
        a = fmaf(fmaf(xr[bl[j][0]+1], wc[j][0], xr[bl[j][0]]*wf[j][0]), wk0, a);
        a = fmaf(fmaf(xr[bl[j][1]+1], wc[j][1], xr[bl[j][1]]*wf[j][1]), wk1, a);
        a = fmaf(fmaf(xr[bl[j][2]+1], wc[j][2], xr[bl[j][2]]*wf[j][2]), wk2, a);
        a = fmaf(fmaf(xr[bl[j][3]+1], wc[j][3], xr[bl[j][3]]*wf[j][3]), wk3, a);
        a = fmaf(fmaf(xr[bl[j][4]+1], wc[j][4], xr[bl[j][4]]*wf[j][4]), wk4, a);
        o[j] = a;
      }
      size_t op = ((size_t)b*CHN + cu)*TLEN + t0 + tx;
      out[op]      = o[0];
      out[op + 64] = o[1];
    }
  }
}

// ---------------------------------------------------------------------------
// k2: fused rp1(conv3, 512->256)+ReLU+rp2(256->1)+bias, bf16 MFMA.
// Fully double-buffered pipeline AT 2 blocks/CU (R3 retry with the LDS fit
// fixed): BM=64 (co-quarter, grid y=4), BN=256, 256 thr (4 waves, wN=wave).
// LDS = 2xWs(15360) + 2xDt(20640) + Ss(1024) = 73 KB -> 2 blocks/CU.
// Per iter: issue next Ws DMA + next def loads (regs) -> COMPUTE(cur)
// (hides load latency) -> cvt+ds_write next Dt -> single barrier (in-flight
// DMA already covered by the compute phase). WST=40 keeps b128 16B-aligned
// (R4 lesson: 44 misaligns; conflicts at 40 cost less than the split reads).
// Partial co-sums accumulate into outs (pre-set to b2 by kPrep).
// ---------------------------------------------------------------------------
#define DMA_WS(dst, ch_) do {                                                  \
  const char* gs = (const char*)(w1t + (size_t)((ch_)*4 + m0)*7680);           \
  char* ld = (char*)&Ws[dst][0];                                               \
  for (int of = tid*16; of < 15360; of += 4096) {                              \
    __builtin_amdgcn_global_load_lds(                                          \
        (const __attribute__((address_space(1))) unsigned int*)(gs + of),      \
        (__attribute__((address_space(3))) unsigned int*)(ld + of), 16, 0, 0); \
  }                                                                            \
} while(0)

#define LOAD_DT(ch_) do {                                                      \
  const float* dpb = def + ((size_t)b*CHN + (ch_)*32 + g*8)*TLEN;              \
  _Pragma("unroll")                                                            \
  for (int s=0;s<4;++s) {                                                      \
    int t = t0 - 1 + tl + s*64;                                                \
    _Pragma("unroll")                                                          \
    for (int j=0;j<8;++j)                                                      \
      rg[s][j] = (t>=0 && t<TLEN) ? dpb[(size_t)j*TLEN + t] : 0.f;             \
  }                                                                            \
  if (tl < 2) {                                                                \
    int t = t0 - 1 + 256 + tl;                                                 \
    _Pragma("unroll")                                                          \
    for (int j=0;j<8;++j)                                                      \
      rt[j] = (t<TLEN) ? dpb[(size_t)j*TLEN + t] : 0.f;                        \
  }                                                                            \
} while(0)

#define WRITE_DT(dst) do {                                                     \
  _Pragma("unroll")                                                            \
  for (int s=0;s<4;++s) {                                                      \
    bf16x8 v;                                                                  \
    _Pragma("unroll")                                                          \
    for (int j=0;j<8;++j) { union{bf16 h; short u;} cv;                        \
      cv.h = __float2bfloat16(rg[s][j]); v[j] = cv.u; }                        \
    *(bf16x8*)((char*)&Dt[dst][0] + (tl + s*64)*80 + g*16) = v;                \
  }                                                                            \
  if (tl < 2) {                                                                \
    bf16x8 v;                                                                  \
    _Pragma("unroll")                                                          \
    for (int j=0;j<8;++j) { union{bf16 h; short u;} cv;                        \
      cv.h = __float2bfloat16(rt[j]); v[j] = cv.u; }                           \
    *(bf16x8*)((char*)&Dt[dst][0] + (256 + tl)*80 + g*16) = v;                 \
  }                                                                            \
} while(0)

#define COMPUTE(cur) do {                                                      \
  _Pragma("unroll")                                                            \
  for (int r=0;r<3;++r) {                                                      \
    bf16x8 af[4], bfr[4];                                                      \
    _Pragma("unroll")                                                          \
    for (int mt=0;mt<4;++mt)                                                   \
      af[mt] = *(const bf16x8*)&Ws[cur][(size_t)(r*64 + mt*16 + ln15)*40 + quad*8];\
    _Pragma("unroll")                                                          \
    for (int nt=0;nt<4;++nt)                                                   \
      bfr[nt] = *(const bf16x8*)&Dt[cur][(size_t)(wN*64 + nt*16 + ln15 + r)*40 + quad*8];\
    _Pragma("unroll")                                                          \
    for (int mt=0;mt<4;++mt)                                                   \
      _Pragma("unroll")                                                        \
      for (int nt=0;nt<4;++nt)                                                 \
        acc[mt][nt] = __builtin_amdgcn_mfma_f32_16x16x32_bf16(                 \
            af[mt], bfr[nt], acc[mt][nt], 0, 0, 0);                            \
  }                                                                            \
} while(0)

__global__ __launch_bounds__(256, 2) void k2(const float* __restrict__ def,
    const bf16* __restrict__ w1t, const float* __restrict__ b1,
    const float* __restrict__ w2, float* __restrict__ outs)
{
  int n0 = blockIdx.x*256;         // BN=256 (divides TLEN)
  int m0 = blockIdx.y;             // 0..3: co quarter
  int b  = n0 / TLEN;
  int t0 = n0 % TLEN;
  int tid  = threadIdx.x;          // 0..255
  int lane = tid & 63;
  int wN   = tid >> 6;             // wave 0..3 = 64-col n group
  int ln15 = lane & 15, quad = lane >> 4;

  __shared__ bf16 Ws[2][3*64*40];  // 30,720 B
  __shared__ bf16 Dt[2][258*40];   // 41,280 B
  __shared__ float Ss[256];

  // Dt staging geometry: wave-uniform ci-octet g, lane-consecutive t rows
  int g  = tid >> 6;               // 0..3 (== wN, wave-uniform)
  int tl = tid & 63;

  f32x4 acc[4][4];
  #pragma unroll
  for (int i=0;i<4;++i)
    #pragma unroll
    for (int j=0;j<4;++j) acc[i][j] = (f32x4){0.f,0.f,0.f,0.f};

  float rg[4][8], rt[8];
  #pragma unroll
  for (int j=0;j<8;++j) rt[j] = 0.f;

  // prologue: stage ch=0 into buffer 0
  DMA_WS(0, 0);
  LOAD_DT(0);
  WRITE_DT(0);
  __syncthreads();                 // drains DMA (vmcnt) + lds writes

  for (int ch=0; ch<16; ++ch) {
    int cur = ch & 1;
    int nxt = cur ^ 1;
    if (ch < 15) {                 // issue next chunk early (uniform branch)
      DMA_WS(nxt, ch+1);
      LOAD_DT(ch+1);
    }
    COMPUTE(cur);                  // ds_read + MFMA hide the in-flight loads
    if (ch < 15)
      WRITE_DT(nxt);               // compiler waits loads just before cvt
    __syncthreads();               // one barrier/iter; DMA covered by compute
  }

  // epilogue: strength[n] += sum_{co in quarter} relu(H[co][n]+b1[co])*w2[co]
  float part[4] = {0.f,0.f,0.f,0.f};
  #pragma unroll
  for (int mt=0;mt<4;++mt) {
    #pragma unroll
    for (int rr=0;rr<4;++rr) {
      int row = m0*64 + mt*16 + quad*4 + rr;
      float bias = b1[row];
      float wv   = w2[row];
      #pragma unroll
      for (int nt=0;nt<4;++nt) {
        float h = acc[mt][nt][rr] + bias;
        h = fmaxf(h, 0.f);
        part[nt] = fmaf(h, wv, part[nt]);
      }
    }
  }
  Ss[tid] = 0.f;
  __syncthreads();
  #pragma unroll
  for (int nt=0;nt<4;++nt)
    atomicAdd(&Ss[wN*64 + nt*16 + ln15], part[nt]);
  __syncthreads();
  atomicAdd(&outs[n0 + tid], Ss[tid]);
}

extern "C" void kernel_launch(void* const* d_in, const int* in_sizes, int n_in,
                              void* d_out, int out_size, void* d_ws, size_t ws_size,
                              hipStream_t stream) {
  const float* x  = (const float*)d_in[0];
  const float* ow = (const float*)d_in[1];
  const float* ob = (const float*)d_in[2];
  const float* mw = (const float*)d_in[3];
  const float* mb = (const float*)d_in[4];
  const float* wg = (const float*)d_in[5];
  const float* w1 = (const float*)d_in[6];
  const float* b1 = (const float*)d_in[7];
  const float* w2 = (const float*)d_in[8];
  const float* b2 = (const float*)d_in[9];

  float* out_def = (float*)d_out;
  float* out_str = out_def + (size_t)BATCH*CHN*TLEN;

  float2* samp = (float2*)d_ws;                                  // 1.31 MB
  bf16*   w1t  = (bf16*)((char*)d_ws + SAMP_BYTES);              // 983 KB
  float*  wpk  = (float*)((char*)d_ws + SAMP_BYTES + W1T_BYTES); // 64 KB

  kPrep<<<dim3(W1T_ELEMS/256 + 64 + 128), 256, 0, stream>>>(
      w1, w1t, ow, mw, wpk, out_str, b2);
  kS   <<<dim3(TLEN/64, BATCH), dim3(64,8), 0, stream>>>(x, wpk, ob, mb, samp);
  kDf  <<<dim3(TLEN/BT, CHN/64, BATCH), dim3(64,4), 0, stream>>>(x, wg, samp, out_def);
  k2   <<<dim3(BATCH*TLEN/256, 4), 256, 0, stream>>>(out_def, w1t, b1, w2, out_str);
}

// Round 6
// 214.567 us; speedup vs baseline: 1.3047x; 1.0672x over previous
//
#include <hip/hip_runtime.h>
#include <hip/hip_bf16.h>

#define CHN 512
#define TLEN 2048
#define KSZ 5
#define BATCH 16

typedef __hip_bfloat16 bf16;
typedef short bf16x8 __attribute__((ext_vector_type(8)));   // 8 bf16 (4 VGPRs)
typedef float f32x4  __attribute__((ext_vector_type(4)));

// ws layout:
//   samp : float2[B*T*5]  (pos, sig)       =  1,310,720 B
//   w1t  : bf16 [16][4][3][64][40]         =    983,040 B   (pre-tiled W1)
//   wpk  : float[512][32]                  =     65,536 B   (packed ow+mw)
//   dtile: bf16 [B][16][2050][32]          = 33,587,200 B   (bf16 def, k2-tiled)
//          row t+1 holds def[b][ch*32+col][t]; rows 0,2049 = zeros (halo)
#define SAMP_BYTES (BATCH*TLEN*KSZ*8)
#define W1T_ELEMS  (16*4*3*64*40)
#define W1T_BYTES  (W1T_ELEMS*2)
#define WPK_BYTES  65536
#define DT_ROWS    2050
#define DT_CHUNK   (DT_ROWS*32)                 // elems per (b,ch)
#define DT_BYTES   ((size_t)BATCH*16*DT_CHUNK*2)

// ---------------------------------------------------------------------------
// kPrep: fused kP (w1 retile) + kW (ow/mw pack) + kZ (outs = b2) +
//        dtile halo-row zeroing. One dispatch.
// ---------------------------------------------------------------------------
__global__ __launch_bounds__(256) void kPrep(const float* __restrict__ w1,
    bf16* __restrict__ w1t, const float* __restrict__ ow,
    const float* __restrict__ mw, float* __restrict__ wpk,
    float* __restrict__ outs, const float* __restrict__ b2p,
    bf16* __restrict__ dt)
{
  int bx = blockIdx.x;
  int tidl = threadIdx.x;
  const int NP = W1T_ELEMS/256;                // 1920
  if (bx < NP) {
    // kP: w1 fp32 [co][ci][r] -> w1t bf16 [ch][q][r][row][40], co = q*64+row
    int idx  = bx*256 + tidl;                  // < 491520
    int c40  = idx % 40;
    int rest = idx / 40;
    int row  = rest & 63;
    int rr   = rest >> 6;          // (ch*4+q)*3 + r
    int r    = rr % 3;
    int cq   = rr / 3;             // ch*4 + q
    int q    = cq & 3;
    int ch   = cq >> 2;
    int co   = q*64 + row;
    float v = 0.f;
    if (c40 < 32) v = w1[(size_t)co*(CHN*3) + (ch*32 + c40)*3 + r];
    w1t[idx] = __float2bfloat16(v);
  } else if (bx < NP + 64) {
    // kW: pack ow/mw -> wpk[c][32]
    int idx = (bx - NP)*256 + tidl;            // < 16384
    int j = idx & 31, c = idx >> 5;
    float v = 0.f;
    if (j < 15)      { int o = j/3,  d = j - o*3;  v = ow[o*(CHN*3) + c*3 + d]; }
    else if (j < 30) { int jj = j-15; int o = jj/3, d = jj - o*3;
                       v = mw[o*(CHN*3) + c*3 + d]; }
    wpk[idx] = v;
  } else if (bx < NP + 192) {
    // kZ: outs = b2 (k2 blocks atomically accumulate on top)
    outs[(bx - NP - 64)*256 + tidl] = b2p[0];
  } else if (dt) {
    // zero dtile halo rows 0 (t=-1) and 2049 (t=2048), all 256 (b,ch) chunks
    int z = (bx - NP - 192)*256 + tidl;        // < 16384
    int chunk = z >> 6;                        // 0..255
    int row   = ((z >> 5) & 1) ? (DT_ROWS-1) : 0;
    int col   = z & 31;
    dt[(size_t)chunk*DT_CHUNK + row*32 + col] = __float2bfloat16(0.f);
  }
}

// ---------------------------------------------------------------------------
// kS: offset conv (out 0..4) + modulator conv (+sigmoid) -> sampling params.
// grid (TLEN/64, B), block (64 t, 8 cg). Each thread reduces 64 channels.
// samp[b,t,k] = (pos, sig); kDf re-derives base/wf/wc (bitwise-identical).
// ---------------------------------------------------------------------------
__global__ __launch_bounds__(512) void kS(const float* __restrict__ x,
    const float* __restrict__ wpk, const float* __restrict__ ob,
    const float* __restrict__ mb, float2* __restrict__ samp)
{
  int b  = blockIdx.y;
  int t0 = blockIdx.x*64;
  int tx = threadIdx.x;
  int cg = threadIdx.y;            // 0..7 (wave-uniform: wave = one tx row)
  int t  = t0 + tx;

  __shared__ float red[8][64][10];

  float acc[10];
  #pragma unroll
  for (int i=0;i<10;++i) acc[i]=0.f;
  const float* xb = x + (size_t)b*CHN*TLEN;
  int c0 = cg*64;
  #pragma unroll 4
  for (int c=c0;c<c0+64;++c) {
    int cu = __builtin_amdgcn_readfirstlane(c);
    const float* wp = wpk + cu*32;             // scalar -> s_load_dwordx8
    const float* xr = xb + (size_t)cu*TLEN;
    float xm = (t>0)      ? xr[t-1] : 0.f;
    float xc = xr[t];
    float xp = (t<TLEN-1) ? xr[t+1] : 0.f;
    #pragma unroll
    for (int o=0;o<5;++o) {
      acc[o]   = fmaf(xm, wp[o*3+0],    acc[o]);
      acc[o]   = fmaf(xc, wp[o*3+1],    acc[o]);
      acc[o]   = fmaf(xp, wp[o*3+2],    acc[o]);
      acc[5+o] = fmaf(xm, wp[15+o*3+0], acc[5+o]);
      acc[5+o] = fmaf(xc, wp[15+o*3+1], acc[5+o]);
      acc[5+o] = fmaf(xp, wp[15+o*3+2], acc[5+o]);
    }
  }
  #pragma unroll
  for (int i=0;i<10;++i) red[cg][tx][i] = acc[i];
  __syncthreads();
  for (int s=4;s>0;s>>=1) {
    if (cg < s) {
      #pragma unroll
      for (int i=0;i<10;++i) red[cg][tx][i] += red[cg+s][tx][i];
    }
    __syncthreads();
  }
  if (cg==0) {
    #pragma unroll
    for (int k=0;k<KSZ;++k) {
      float off = red[0][tx][k]   + ob[k];
      float mv  = red[0][tx][5+k] + mb[k];
      float sig = 1.f/(1.f + expf(-mv));
      float pos = (float)(t + k - 2) + off;
      pos = fminf(fmaxf(pos, 0.f), (float)(TLEN-1));
      samp[((size_t)b*TLEN + t)*KSZ + k] = make_float2(pos, sig);
    }
  }
}

// ---------------------------------------------------------------------------
// kDf: deformable sampling w/ diagonal weight — LDS-tiled.
// grid (T/128, C/64, B), block (64,4). Block stages x[c0..c0+63][lo..lo+159]
// into LDS via global_load_lds DMA, serves all gathers from LDS. Thread owns
// t = {t0+tx, t0+64+tx} x 16 consecutive c-rows. If WDT, also packs its 16
// bf16 per t (contiguous ci) and stores 32B to dtile (k2 operand, no re-cvt).
// Block-uniform fallback to global gathers if any base escapes the halo.
// ---------------------------------------------------------------------------
#define BT   128
#define HALO 16
#define XLEN 160   // BT + 2*HALO

template<bool WDT>
__global__ __launch_bounds__(256) void kDf(const float* __restrict__ x,
    const float* __restrict__ wgt, const float2* __restrict__ sampg,
    float* __restrict__ out, bf16* __restrict__ dt)
{
  int b  = blockIdx.z;
  int c0 = blockIdx.y*64;
  int t0 = blockIdx.x*BT;
  int tx = threadIdx.x, cy = threadIdx.y;
  int tid = cy*64 + tx;

  __shared__ float  xs[64*XLEN];    // 40,960 B
  __shared__ float2 sp[BT*KSZ];     //  5,120 B
  __shared__ int okf;

  int lo = min(max(t0 - HALO, 0), TLEN - XLEN);   // window always in-bounds

  if (tid == 0) okf = 1;
  for (int i = tid; i < BT*KSZ; i += 256)
    sp[i] = sampg[((size_t)b*TLEN + t0)*KSZ + i];

  // --- DMA x tile: 64 rows x 160 floats = 2560 float4 chunks, 10/thread.
  const float* xb = x + (size_t)b*CHN*TLEN;
  #pragma unroll
  for (int it = 0; it < 10; ++it) {
    int idx = tid + it*256;
    int c  = idx / 40;             // local c row
    int c4 = idx - c*40;           // float4 within row
    const float* src = xb + (size_t)(c0 + c)*TLEN + lo + c4*4;
    __builtin_amdgcn_global_load_lds(
        (const __attribute__((address_space(1))) unsigned int*)src,
        (__attribute__((address_space(3))) unsigned int*)&xs[idx*4],
        16, 0, 0);
  }
  __syncthreads();   // drains DMA (vmcnt) + sp writes (lgkm)

  // --- expand sampling params for this thread's 2x5 taps
  int   bl[2][KSZ];
  float wf[2][KSZ], wc[2][KSZ];
  bool ok = true;
  #pragma unroll
  for (int j=0;j<2;++j)
    #pragma unroll
    for (int k=0;k<KSZ;++k) {
      float2 s = sp[(j*64+tx)*KSZ + k];
      float pos = s.x, sig = s.y;
      float pf = floorf(pos), pc = ceilf(pos);
      int base = min((int)pf, TLEN-2);
      wf[j][k] = (pc - pos)*sig;     // ref quirk: pos integral -> wf=wc=0
      wc[j][k] = (pos - pf)*sig;
      int bloc = base - lo;
      bl[j][k] = bloc;
      ok = ok && (bloc >= 0) && (bloc <= XLEN-2);
    }
  if (!ok) okf = 0;
  __syncthreads();
  int fast = okf;    // block-uniform branch

  unsigned pk0[8], pk1[8];
  if (fast) {
    #pragma unroll
    for (int i=0;i<16;++i) {         // FULL unroll: pk[] statically indexed
      int cl = cy*16 + i;
      int cu = __builtin_amdgcn_readfirstlane(c0 + cl);
      const float* wd = wgt + (size_t)cu*(CHN*KSZ) + (size_t)cu*KSZ;  // diag
      float w0 = wd[0], w1v = wd[1], w2v = wd[2], w3 = wd[3], w4 = wd[4];
      const float* xr = xs + cl*XLEN;
      float o0, o1;
      {
        float a = 0.f;
        a = fmaf(fmaf(xr[bl[0][0]+1], wc[0][0], xr[bl[0][0]]*wf[0][0]), w0,  a);
        a = fmaf(fmaf(xr[bl[0][1]+1], wc[0][1], xr[bl[0][1]]*wf[0][1]), w1v, a);
        a = fmaf(fmaf(xr[bl[0][2]+1], wc[0][2], xr[bl[0][2]]*wf[0][2]), w2v, a);
        a = fmaf(fmaf(xr[bl[0][3]+1], wc[0][3], xr[bl[0][3]]*wf[0][3]), w3,  a);
        a = fmaf(fmaf(xr[bl[0][4]+1], wc[0][4], xr[bl[0][4]]*wf[0][4]), w4,  a);
        o0 = a;
      }
      {
        float a = 0.f;
        a = fmaf(fmaf(xr[bl[1][0]+1], wc[1][0], xr[bl[1][0]]*wf[1][0]), w0,  a);
        a = fmaf(fmaf(xr[bl[1][1]+1], wc[1][1], xr[bl[1][1]]*wf[1][1]), w1v, a);
        a = fmaf(fmaf(xr[bl[1][2]+1], wc[1][2], xr[bl[1][2]]*wf[1][2]), w2v, a);
        a = fmaf(fmaf(xr[bl[1][3]+1], wc[1][3], xr[bl[1][3]]*wf[1][3]), w3,  a);
        a = fmaf(fmaf(xr[bl[1][4]+1], wc[1][4], xr[bl[1][4]]*wf[1][4]), w4,  a);
        o1 = a;
      }
      size_t op = ((size_t)b*CHN + cu)*TLEN + t0 + tx;
      out[op]      = o0;
      out[op + 64] = o1;
      if (WDT) {
        union { bf16 h; unsigned short u; } cv0, cv1;
        cv0.h = __float2bfloat16(o0);
        cv1.h = __float2bfloat16(o1);
        if (i & 1) { pk0[i>>1] |= (unsigned)cv0.u << 16;
                     pk1[i>>1] |= (unsigned)cv1.u << 16; }
        else       { pk0[i>>1]  = cv0.u;  pk1[i>>1]  = cv1.u; }
      }
    }
  } else {
    // slow path (never taken with bench weights): global gathers, same math
    #pragma unroll
    for (int i=0;i<16;++i) {
      int cl = cy*16 + i;
      int cu = __builtin_amdgcn_readfirstlane(c0 + cl);
      const float* wd = wgt + (size_t)cu*(CHN*KSZ) + (size_t)cu*KSZ;
      float wk0 = wd[0], wk1 = wd[1], wk2 = wd[2], wk3 = wd[3], wk4 = wd[4];
      const float* xr = xb + (size_t)cu*TLEN + lo;   // xr[bl] == x[base]
      float o[2];
      #pragma unroll
      for (int j=0;j<2;++j) {
        float a = 0.f;
        a = fmaf(fmaf(xr[bl[j][0]+1], wc[j][0], xr[bl[j][0]]*wf[j][0]), wk0, a);
        a = fmaf(fmaf(xr[bl[j][1]+1], wc[j][1], xr[bl[j][1]]*wf[j][1]), wk1, a);
        a = fmaf(fmaf(xr[bl[j][2]+1], wc[j][2], xr[bl[j][2]]*wf[j][2]), wk2, a);
        a = fmaf(fmaf(xr[bl[j][3]+1], wc[j][3], xr[bl[j][3]]*wf[j][3]), wk3, a);
        a = fmaf(fmaf(xr[bl[j][4]+1], wc[j][4], xr[bl[j][4]]*wf[j][4]), wk4, a);
        o[j] = a;
      }
      size_t op = ((size_t)b*CHN + cu)*TLEN + t0 + tx;
      out[op]      = o[0];
      out[op + 64] = o[1];
      if (WDT) {
        union { bf16 h; unsigned short u; } cv0, cv1;
        cv0.h = __float2bfloat16(o[0]);
        cv1.h = __float2bfloat16(o[1]);
        if (i & 1) { pk0[i>>1] |= (unsigned)cv0.u << 16;
                     pk1[i>>1] |= (unsigned)cv1.u << 16; }
        else       { pk0[i>>1]  = cv0.u;  pk1[i>>1]  = cv1.u; }
      }
    }
  }

  if (WDT) {
    // thread's 16 bf16 are ci-contiguous: chunk (b,ch), row t+1, col half
    int ch   = (c0 >> 5) + (cy >> 1);
    int colb = (cy & 1)*16;
    bf16* p0 = dt + (size_t)(b*16 + ch)*DT_CHUNK
                  + (size_t)(t0 + tx + 1)*32 + colb;
    *(uint4*)p0       = make_uint4(pk0[0], pk0[1], pk0[2], pk0[3]);
    *((uint4*)p0 + 1) = make_uint4(pk0[4], pk0[5], pk0[6], pk0[7]);
    bf16* p1 = p0 + 64*32;
    *(uint4*)p1       = make_uint4(pk1[0], pk1[1], pk1[2], pk1[3]);
    *((uint4*)p1 + 1) = make_uint4(pk1[4], pk1[5], pk1[6], pk1[7]);
  }
}

// ---------------------------------------------------------------------------
// k2d: fused rp1(conv3, 512->256)+ReLU+rp2(256->1)+bias, bf16 MFMA.
// BOTH operands staged by pure global_load_lds DMA (Ws from w1t, Dt from
// dtile -- no loads/cvt/ds_write in the loop). Double-buffered, 2 blocks/CU
// (LDS 64.8 KB). BM=64 (co-quarter, grid y=4), BN=256, 256 thr (4 waves).
// Per iter: issue next Ws+Dt DMA -> COMPUTE(cur) hides DMA latency ->
// single barrier. Partial co-sums atomicAdd into outs (pre-set to b2).
// ---------------------------------------------------------------------------
#define DMA_W2(dst, ch_) do {                                                  \
  const char* gs = (const char*)(w1t + (size_t)((ch_)*4 + m0)*7680);           \
  char* ld = (char*)&Ws[dst][0];                                               \
  for (int of = tid*16; of < 15360; of += 4096) {                              \
    __builtin_amdgcn_global_load_lds(                                          \
        (const __attribute__((address_space(1))) unsigned int*)(gs + of),      \
        (__attribute__((address_space(3))) unsigned int*)(ld + of), 16, 0, 0); \
  }                                                                            \
} while(0)

#define DMA_D2(dst, ch_) do {                                                  \
  const char* gs = (const char*)(dt + (size_t)(b*16 + (ch_))*DT_CHUNK          \
                                    + (size_t)t0*32);                          \
  char* ld = (char*)&Dt[dst][0];                                               \
  for (int of = tid*16; of < 16512; of += 4096) {                              \
    __builtin_amdgcn_global_load_lds(                                          \
        (const __attribute__((address_space(1))) unsigned int*)(gs + of),      \
        (__attribute__((address_space(3))) unsigned int*)(ld + of), 16, 0, 0); \
  }                                                                            \
} while(0)

#define COMPUTE2(cur) do {                                                     \
  _Pragma("unroll")                                                            \
  for (int r=0;r<3;++r) {                                                      \
    bf16x8 af[4], bfr[4];                                                      \
    _Pragma("unroll")                                                          \
    for (int mt=0;mt<4;++mt)                                                   \
      af[mt] = *(const bf16x8*)&Ws[cur][(size_t)(r*64 + mt*16 + ln15)*40 + quad*8];\
    _Pragma("unroll")                                                          \
    for (int nt=0;nt<4;++nt)                                                   \
      bfr[nt] = *(const bf16x8*)&Dt[cur][(size_t)(wN*64 + nt*16 + ln15 + r)*32 + quad*8];\
    _Pragma("unroll")                                                          \
    for (int mt=0;mt<4;++mt)                                                   \
      _Pragma("unroll")                                                        \
      for (int nt=0;nt<4;++nt)                                                 \
        acc[mt][nt] = __builtin_amdgcn_mfma_f32_16x16x32_bf16(                 \
            af[mt], bfr[nt], acc[mt][nt], 0, 0, 0);                            \
  }                                                                            \
} while(0)

__global__ __launch_bounds__(256, 2) void k2d(const bf16* __restrict__ dt,
    const bf16* __restrict__ w1t, const float* __restrict__ b1,
    const float* __restrict__ w2, float* __restrict__ outs)
{
  int n0 = blockIdx.x*256;         // BN=256 (divides TLEN)
  int m0 = blockIdx.y;             // 0..3: co quarter
  int b  = n0 / TLEN;
  int t0 = n0 % TLEN;
  int tid  = threadIdx.x;          // 0..255
  int lane = tid & 63;
  int wN   = tid >> 6;             // wave 0..3 = 64-col n group
  int ln15 = lane & 15, quad = lane >> 4;

  __shared__ bf16 Ws[2][3*64*40];  // 30,720 B
  __shared__ bf16 Dt[2][258*32];   // 33,024 B
  __shared__ float Ss[256];

  f32x4 acc[4][4];
  #pragma unroll
  for (int i=0;i<4;++i)
    #pragma unroll
    for (int j=0;j<4;++j) acc[i][j] = (f32x4){0.f,0.f,0.f,0.f};

  // prologue: stage ch=0 into buffer 0
  DMA_W2(0, 0);
  DMA_D2(0, 0);
  __syncthreads();                 // drains DMA (vmcnt)

  for (int ch=0; ch<16; ++ch) {
    int cur = ch & 1;
    int nxt = cur ^ 1;
    if (ch < 15) {                 // issue next chunk early (uniform branch)
      DMA_W2(nxt, ch+1);
      DMA_D2(nxt, ch+1);
    }
    COMPUTE2(cur);                 // ds_read + MFMA hide the in-flight DMA
    __syncthreads();               // one barrier/iter; drains nxt DMA
  }

  // epilogue: strength[n] += sum_{co in quarter} relu(H[co][n]+b1[co])*w2[co]
  float part[4] = {0.f,0.f,0.f,0.f};
  #pragma unroll
  for (int mt=0;mt<4;++mt) {
    #pragma unroll
    for (int rr=0;rr<4;++rr) {
      int row = m0*64 + mt*16 + quad*4 + rr;
      float bias = b1[row];
      float wv   = w2[row];
      #pragma unroll
      for (int nt=0;nt<4;++nt) {
        float h = acc[mt][nt][rr] + bias;
        h = fmaxf(h, 0.f);
        part[nt] = fmaf(h, wv, part[nt]);
      }
    }
  }
  Ss[tid] = 0.f;
  __syncthreads();
  #pragma unroll
  for (int nt=0;nt<4;++nt)
    atomicAdd(&Ss[wN*64 + nt*16 + ln15], part[nt]);
  __syncthreads();
  atomicAdd(&outs[n0 + tid], Ss[tid]);
}

// ---------------------------------------------------------------------------
// k2r: R5 fallback (register-staged def) -- used only if ws too small for
// dtile. Identical to the R5-measured 51.9us kernel.
// ---------------------------------------------------------------------------
#define DMA_WSR(dst, ch_) do {                                                 \
  const char* gs = (const char*)(w1t + (size_t)((ch_)*4 + m0)*7680);           \
  char* ld = (char*)&Ws[dst][0];                                               \
  for (int of = tid*16; of < 15360; of += 4096) {                              \
    __builtin_amdgcn_global_load_lds(                                          \
        (const __attribute__((address_space(1))) unsigned int*)(gs + of),      \
        (__attribute__((address_space(3))) unsigned int*)(ld + of), 16, 0, 0); \
  }                                                                            \
} while(0)

#define LOAD_DTR(ch_) do {                                                     \
  const float* dpb = def + ((size_t)b*CHN + (ch_)*32 + g*8)*TLEN;              \
  _Pragma("unroll")                                                            \
  for (int s=0;s<4;++s) {                                                      \
    int t = t0 - 1 + tl + s*64;                                                \
    _Pragma("unroll")                                                          \
    for (int j=0;j<8;++j)                                                      \
      rg[s][j] = (t>=0 && t<TLEN) ? dpb[(size_t)j*TLEN + t] : 0.f;             \
  }                                                                            \
  if (tl < 2) {                                                                \
    int t = t0 - 1 + 256 + tl;                                                 \
    _Pragma("unroll")                                                          \
    for (int j=0;j<8;++j)                                                      \
      rt[j] = (t<TLEN) ? dpb[(size_t)j*TLEN + t] : 0.f;                        \
  }                                                                            \
} while(0)

#define WRITE_DTR(dst) do {                                                    \
  _Pragma("unroll")                                                            \
  for (int s=0;s<4;++s) {                                                      \
    bf16x8 v;                                                                  \
    _Pragma("unroll")                                                          \
    for (int j=0;j<8;++j) { union{bf16 h; short u;} cv;                        \
      cv.h = __float2bfloat16(rg[s][j]); v[j] = cv.u; }                        \
    *(bf16x8*)((char*)&Dt[dst][0] + (tl + s*64)*80 + g*16) = v;                \
  }                                                                            \
  if (tl < 2) {                                                                \
    bf16x8 v;                                                                  \
    _Pragma("unroll")                                                          \
    for (int j=0;j<8;++j) { union{bf16 h; short u;} cv;                        \
      cv.h = __float2bfloat16(rt[j]); v[j] = cv.u; }                           \
    *(bf16x8*)((char*)&Dt[dst][0] + (256 + tl)*80 + g*16) = v;                 \
  }                                                                            \
} while(0)

#define COMPUTER(cur) do {                                                     \
  _Pragma("unroll")                                                            \
  for (int r=0;r<3;++r) {                                                      \
    bf16x8 af[4], bfr[4];                                                      \
    _Pragma("unroll")                                                          \
    for (int mt=0;mt<4;++mt)                                                   \
      af[mt] = *(const bf16x8*)&Ws[cur][(size_t)(r*64 + mt*16 + ln15)*40 + quad*8];\
    _Pragma("unroll")                                                          \
    for (int nt=0;nt<4;++nt)                                                   \
      bfr[nt] = *(const bf16x8*)&Dt[cur][(size_t)(wN*64 + nt*16 + ln15 + r)*40 + quad*8];\
    _Pragma("unroll")                                                          \
    for (int mt=0;mt<4;++mt)                                                   \
      _Pragma("unroll")                                                        \
      for (int nt=0;nt<4;++nt)                                                 \
        acc[mt][nt] = __builtin_amdgcn_mfma_f32_16x16x32_bf16(                 \
            af[mt], bfr[nt], acc[mt][nt], 0, 0, 0);                            \
  }                                                                            \
} while(0)

__global__ __launch_bounds__(256, 2) void k2r(const float* __restrict__ def,
    const bf16* __restrict__ w1t, const float* __restrict__ b1,
    const float* __restrict__ w2, float* __restrict__ outs)
{
  int n0 = blockIdx.x*256;
  int m0 = blockIdx.y;
  int b  = n0 / TLEN;
  int t0 = n0 % TLEN;
  int tid  = threadIdx.x;
  int lane = tid & 63;
  int wN   = tid >> 6;
  int ln15 = lane & 15, quad = lane >> 4;

  __shared__ bf16 Ws[2][3*64*40];
  __shared__ bf16 Dt[2][258*40];
  __shared__ float Ss[256];

  int g  = tid >> 6;
  int tl = tid & 63;

  f32x4 acc[4][4];
  #pragma unroll
  for (int i=0;i<4;++i)
    #pragma unroll
    for (int j=0;j<4;++j) acc[i][j] = (f32x4){0.f,0.f,0.f,0.f};

  float rg[4][8], rt[8];
  #pragma unroll
  for (int j=0;j<8;++j) rt[j] = 0.f;

  DMA_WSR(0, 0);
  LOAD_DTR(0);
  WRITE_DTR(0);
  __syncthreads();

  for (int ch=0; ch<16; ++ch) {
    int cur = ch & 1;
    int nxt = cur ^ 1;
    if (ch < 15) {
      DMA_WSR(nxt, ch+1);
      LOAD_DTR(ch+1);
    }
    COMPUTER(cur);
    if (ch < 15)
      WRITE_DTR(nxt);
    __syncthreads();
  }

  float part[4] = {0.f,0.f,0.f,0.f};
  #pragma unroll
  for (int mt=0;mt<4;++mt) {
    #pragma unroll
    for (int rr=0;rr<4;++rr) {
      int row = m0*64 + mt*16 + quad*4 + rr;
      float bias = b1[row];
      float wv   = w2[row];
      #pragma unroll
      for (int nt=0;nt<4;++nt) {
        float h = acc[mt][nt][rr] + bias;
        h = fmaxf(h, 0.f);
        part[nt] = fmaf(h, wv, part[nt]);
      }
    }
  }
  Ss[tid] = 0.f;
  __syncthreads();
  #pragma unroll
  for (int nt=0;nt<4;++nt)
    atomicAdd(&Ss[wN*64 + nt*16 + ln15], part[nt]);
  __syncthreads();
  atomicAdd(&outs[n0 + tid], Ss[tid]);
}

extern "C" void kernel_launch(void* const* d_in, const int* in_sizes, int n_in,
                              void* d_out, int out_size, void* d_ws, size_t ws_size,
                              hipStream_t stream) {
  const float* x  = (const float*)d_in[0];
  const float* ow = (const float*)d_in[1];
  const float* ob = (const float*)d_in[2];
  const float* mw = (const float*)d_in[3];
  const float* mb = (const float*)d_in[4];
  const float* wg = (const float*)d_in[5];
  const float* w1 = (const float*)d_in[6];
  const float* b1 = (const float*)d_in[7];
  const float* w2 = (const float*)d_in[8];
  const float* b2 = (const float*)d_in[9];

  float* out_def = (float*)d_out;
  float* out_str = out_def + (size_t)BATCH*CHN*TLEN;

  float2* samp = (float2*)d_ws;                                  // 1.31 MB
  bf16*   w1t  = (bf16*)((char*)d_ws + SAMP_BYTES);              // 983 KB
  float*  wpk  = (float*)((char*)d_ws + SAMP_BYTES + W1T_BYTES); // 64 KB

  size_t need = (size_t)SAMP_BYTES + W1T_BYTES + WPK_BYTES + DT_BYTES;
  bf16* dt = (ws_size >= need)
      ? (bf16*)((char*)d_ws + SAMP_BYTES + W1T_BYTES + WPK_BYTES)
      : nullptr;

  kPrep<<<dim3(W1T_ELEMS/256 + 256), 256, 0, stream>>>(
      w1, w1t, ow, mw, wpk, out_str, b2, dt);
  kS   <<<dim3(TLEN/64, BATCH), dim3(64,8), 0, stream>>>(x, wpk, ob, mb, samp);
  if (dt) {
    kDf<true> <<<dim3(TLEN/BT, CHN/64, BATCH), dim3(64,4), 0, stream>>>(
        x, wg, samp, out_def, dt);
    k2d<<<dim3(BATCH*TLEN/256, 4), 256, 0, stream>>>(dt, w1t, b1, w2, out_str);
  } else {
    kDf<false><<<dim3(TLEN/BT, CHN/64, BATCH), dim3(64,4), 0, stream>>>(
        x, wg, samp, out_def, nullptr);
    k2r<<<dim3(BATCH*TLEN/256, 4), 256, 0, stream>>>(out_def, w1t, b1, w2, out_str);
  }
}

// Round 7
// 209.148 us; speedup vs baseline: 1.3385x; 1.0259x over previous
//
#include <hip/hip_runtime.h>
#include <hip/hip_bf16.h>

#define CHN 512
#define TLEN 2048
#define KSZ 5
#define BATCH 16

typedef __hip_bfloat16 bf16;
typedef short bf16x8 __attribute__((ext_vector_type(8)));   // 8 bf16 (4 VGPRs)
typedef float f32x4  __attribute__((ext_vector_type(4)));

// ws layout:
//   samp : float2[B*T*5]  (pos, sig)       =  1,310,720 B
//   w1t  : bf16 [16][4][3][64][40]         =    983,040 B   (pre-tiled W1)
//   wpk  : float[512][32]                  =     65,536 B   (packed ow+mw)
//   dtile: bf16 [B][16][2050][32]          = 33,587,200 B   (bf16 def, k2-tiled)
//          row t+1 holds def[b][ch*32+col][t]; rows 0,2049 = zeros (halo)
#define SAMP_BYTES (BATCH*TLEN*KSZ*8)
#define W1T_ELEMS  (16*4*3*64*40)
#define W1T_BYTES  (W1T_ELEMS*2)
#define WPK_BYTES  65536
#define DT_ROWS    2050
#define DT_CHUNK   (DT_ROWS*32)                 // elems per (b,ch)
#define DT_BYTES   ((size_t)BATCH*16*DT_CHUNK*2)

// ---------------------------------------------------------------------------
// kPrep: fused kP (w1 retile) + kW (ow/mw pack) + kZ (outs = b2) +
//        dtile halo-row zeroing. One dispatch.
// ---------------------------------------------------------------------------
__global__ __launch_bounds__(256) void kPrep(const float* __restrict__ w1,
    bf16* __restrict__ w1t, const float* __restrict__ ow,
    const float* __restrict__ mw, float* __restrict__ wpk,
    float* __restrict__ outs, const float* __restrict__ b2p,
    bf16* __restrict__ dt)
{
  int bx = blockIdx.x;
  int tidl = threadIdx.x;
  const int NP = W1T_ELEMS/256;                // 1920
  if (bx < NP) {
    // kP: w1 fp32 [co][ci][r] -> w1t bf16 [ch][q][r][row][40], co = q*64+row
    int idx  = bx*256 + tidl;                  // < 491520
    int c40  = idx % 40;
    int rest = idx / 40;
    int row  = rest & 63;
    int rr   = rest >> 6;          // (ch*4+q)*3 + r
    int r    = rr % 3;
    int cq   = rr / 3;             // ch*4 + q
    int q    = cq & 3;
    int ch   = cq >> 2;
    int co   = q*64 + row;
    float v = 0.f;
    if (c40 < 32) v = w1[(size_t)co*(CHN*3) + (ch*32 + c40)*3 + r];
    w1t[idx] = __float2bfloat16(v);
  } else if (bx < NP + 64) {
    // kW: pack ow/mw -> wpk[c][32]
    int idx = (bx - NP)*256 + tidl;            // < 16384
    int j = idx & 31, c = idx >> 5;
    float v = 0.f;
    if (j < 15)      { int o = j/3,  d = j - o*3;  v = ow[o*(CHN*3) + c*3 + d]; }
    else if (j < 30) { int jj = j-15; int o = jj/3, d = jj - o*3;
                       v = mw[o*(CHN*3) + c*3 + d]; }
    wpk[idx] = v;
  } else if (bx < NP + 192) {
    // kZ: outs = b2 (k2 blocks atomically accumulate on top)
    outs[(bx - NP - 64)*256 + tidl] = b2p[0];
  } else if (dt) {
    // zero dtile halo rows 0 (t=-1) and 2049 (t=2048), all 256 (b,ch) chunks
    int z = (bx - NP - 192)*256 + tidl;        // < 16384
    int chunk = z >> 6;                        // 0..255
    int row   = ((z >> 5) & 1) ? (DT_ROWS-1) : 0;
    int col   = z & 31;
    dt[(size_t)chunk*DT_CHUNK + row*32 + col] = __float2bfloat16(0.f);
  }
}

// ---------------------------------------------------------------------------
// kS: offset conv (out 0..4) + modulator conv (+sigmoid) -> sampling params.
// grid (TLEN/64, B), block (64 t, 8 cg). Each thread reduces 64 channels.
// samp[b,t,k] = (pos, sig); kDf re-derives base/wf/wc (bitwise-identical).
// ---------------------------------------------------------------------------
__global__ __launch_bounds__(512) void kS(const float* __restrict__ x,
    const float* __restrict__ wpk, const float* __restrict__ ob,
    const float* __restrict__ mb, float2* __restrict__ samp)
{
  int b  = blockIdx.y;
  int t0 = blockIdx.x*64;
  int tx = threadIdx.x;
  int cg = threadIdx.y;            // 0..7 (wave-uniform: wave = one tx row)
  int t  = t0 + tx;

  __shared__ float red[8][64][10];

  float acc[10];
  #pragma unroll
  for (int i=0;i<10;++i) acc[i]=0.f;
  const float* xb = x + (size_t)b*CHN*TLEN;
  int c0 = cg*64;
  #pragma unroll 4
  for (int c=c0;c<c0+64;++c) {
    int cu = __builtin_amdgcn_readfirstlane(c);
    const float* wp = wpk + cu*32;             // scalar -> s_load_dwordx8
    const float* xr = xb + (size_t)cu*TLEN;
    float xm = (t>0)      ? xr[t-1] : 0.f;
    float xc = xr[t];
    float xp = (t<TLEN-1) ? xr[t+1] : 0.f;
    #pragma unroll
    for (int o=0;o<5;++o) {
      acc[o]   = fmaf(xm, wp[o*3+0],    acc[o]);
      acc[o]   = fmaf(xc, wp[o*3+1],    acc[o]);
      acc[o]   = fmaf(xp, wp[o*3+2],    acc[o]);
      acc[5+o] = fmaf(xm, wp[15+o*3+0], acc[5+o]);
      acc[5+o] = fmaf(xc, wp[15+o*3+1], acc[5+o]);
      acc[5+o] = fmaf(xp, wp[15+o*3+2], acc[5+o]);
    }
  }
  #pragma unroll
  for (int i=0;i<10;++i) red[cg][tx][i] = acc[i];
  __syncthreads();
  for (int s=4;s>0;s>>=1) {
    if (cg < s) {
      #pragma unroll
      for (int i=0;i<10;++i) red[cg][tx][i] += red[cg+s][tx][i];
    }
    __syncthreads();
  }
  if (cg==0) {
    #pragma unroll
    for (int k=0;k<KSZ;++k) {
      float off = red[0][tx][k]   + ob[k];
      float mv  = red[0][tx][5+k] + mb[k];
      float sig = 1.f/(1.f + expf(-mv));
      float pos = (float)(t + k - 2) + off;
      pos = fminf(fmaxf(pos, 0.f), (float)(TLEN-1));
      samp[((size_t)b*TLEN + t)*KSZ + k] = make_float2(pos, sig);
    }
  }
}

// ---------------------------------------------------------------------------
// kDf: deformable sampling w/ diagonal weight — wave-synchronous, NO barrier.
// grid (T/128, C/16, B), block = ONE wave (64 thr). The wave stages its own
// 16 c-rows of x into LDS (10.25 KB -> ~15 waves/CU), fences with a per-wave
// vmcnt(0), and serves all gathers from LDS. Sampling params read directly
// from sampg (L2/L3-hot). Thread owns t = {t0+tx, t0+64+tx} x 16 c-rows.
// If WDT, packs 16 ci-contiguous bf16 per t and stores 32 B to dtile.
// Wave-uniform fallback to global gathers if any base escapes the halo.
// ---------------------------------------------------------------------------
#define BT   128
#define HALO 16
#define XLEN 160   // BT + 2*HALO

template<bool WDT>
__global__ __launch_bounds__(64) void kDf(const float* __restrict__ x,
    const float* __restrict__ wgt, const float2* __restrict__ sampg,
    float* __restrict__ out, bf16* __restrict__ dt)
{
  int b  = blockIdx.z;
  int c0 = blockIdx.y*16;
  int t0 = blockIdx.x*BT;
  int tx = threadIdx.x;

  __shared__ float xs[16*XLEN];     // 10,240 B

  int lo = min(max(t0 - HALO, 0), TLEN - XLEN);   // window always in-bounds
                                                  // (and 16B-aligned: lo%16==0)

  // --- DMA own x tile: 16 rows x 160 floats = 640 float4 chunks, 10/lane.
  const float* xb = x + (size_t)b*CHN*TLEN;
  #pragma unroll
  for (int it = 0; it < 10; ++it) {
    int idx = tx + it*64;
    int c  = idx / 40;             // local c row
    int c4 = idx - c*40;           // float4 within row
    const float* src = xb + (size_t)(c0 + c)*TLEN + lo + c4*4;
    __builtin_amdgcn_global_load_lds(
        (const __attribute__((address_space(1))) unsigned int*)src,
        (__attribute__((address_space(3))) unsigned int*)&xs[idx*4],
        16, 0, 0);
  }

  // --- sampling params straight from global (covers DMA latency with VALU)
  int   bl[2][KSZ];
  float wf[2][KSZ], wc[2][KSZ];
  bool ok = true;
  #pragma unroll
  for (int j=0;j<2;++j)
    #pragma unroll
    for (int k=0;k<KSZ;++k) {
      float2 s = sampg[((size_t)b*TLEN + t0 + j*64 + tx)*KSZ + k];
      float pos = s.x, sig = s.y;
      float pf = floorf(pos), pc = ceilf(pos);
      int base = min((int)pf, TLEN-2);
      wf[j][k] = (pc - pos)*sig;     // ref quirk: pos integral -> wf=wc=0
      wc[j][k] = (pos - pf)*sig;
      int bloc = base - lo;
      bl[j][k] = bloc;
      ok = ok && (bloc >= 0) && (bloc <= XLEN-2);
    }
  int fast = __all((int)ok);        // wave-uniform branch

  // fence: own-wave DMA -> LDS reads (no barrier; LDS is private to wave)
  asm volatile("s_waitcnt vmcnt(0)" ::: "memory");
  __builtin_amdgcn_sched_barrier(0);

  unsigned pk0[8], pk1[8];
  if (fast) {
    #pragma unroll
    for (int i=0;i<16;++i) {         // FULL unroll: pk[] statically indexed
      int cu = __builtin_amdgcn_readfirstlane(c0 + i);
      const float* wd = wgt + (size_t)cu*(CHN*KSZ) + (size_t)cu*KSZ;  // diag
      float w0 = wd[0], w1v = wd[1], w2v = wd[2], w3 = wd[3], w4 = wd[4];
      const float* xr = xs + i*XLEN;
      float o0, o1;
      {
        float a = 0.f;
        a = fmaf(fmaf(xr[bl[0][0]+1], wc[0][0], xr[bl[0][0]]*wf[0][0]), w0,  a);
        a = fmaf(fmaf(xr[bl[0][1]+1], wc[0][1], xr[bl[0][1]]*wf[0][1]), w1v, a);
        a = fmaf(fmaf(xr[bl[0][2]+1], wc[0][2], xr[bl[0][2]]*wf[0][2]), w2v, a);
        a = fmaf(fmaf(xr[bl[0][3]+1], wc[0][3], xr[bl[0][3]]*wf[0][3]), w3,  a);
        a = fmaf(fmaf(xr[bl[0][4]+1], wc[0][4], xr[bl[0][4]]*wf[0][4]), w4,  a);
        o0 = a;
      }
      {
        float a = 0.f;
        a = fmaf(fmaf(xr[bl[1][0]+1], wc[1][0], xr[bl[1][0]]*wf[1][0]), w0,  a);
        a = fmaf(fmaf(xr[bl[1][1]+1], wc[1][1], xr[bl[1][1]]*wf[1][1]), w1v, a);
        a = fmaf(fmaf(xr[bl[1][2]+1], wc[1][2], xr[bl[1][2]]*wf[1][2]), w2v, a);
        a = fmaf(fmaf(xr[bl[1][3]+1], wc[1][3], xr[bl[1][3]]*wf[1][3]), w3,  a);
        a = fmaf(fmaf(xr[bl[1][4]+1], wc[1][4], xr[bl[1][4]]*wf[1][4]), w4,  a);
        o1 = a;
      }
      size_t op = ((size_t)b*CHN + cu)*TLEN + t0 + tx;
      out[op]      = o0;
      out[op + 64] = o1;
      if (WDT) {
        union { bf16 h; unsigned short u; } cv0, cv1;
        cv0.h = __float2bfloat16(o0);
        cv1.h = __float2bfloat16(o1);
        if (i & 1) { pk0[i>>1] |= (unsigned)cv0.u << 16;
                     pk1[i>>1] |= (unsigned)cv1.u << 16; }
        else       { pk0[i>>1]  = cv0.u;  pk1[i>>1]  = cv1.u; }
      }
    }
  } else {
    // slow path (never taken with bench weights): global gathers, same math
    #pragma unroll
    for (int i=0;i<16;++i) {
      int cu = __builtin_amdgcn_readfirstlane(c0 + i);
      const float* wd = wgt + (size_t)cu*(CHN*KSZ) + (size_t)cu*KSZ;
      float wk0 = wd[0], wk1 = wd[1], wk2 = wd[2], wk3 = wd[3], wk4 = wd[4];
      const float* xr = xb + (size_t)cu*TLEN + lo;   // xr[bl] == x[base]
      float o[2];
      #pragma unroll
      for (int j=0;j<2;++j) {
        float a = 0.f;
        a = fmaf(fmaf(xr[bl[j][0]+1], wc[j][0], xr[bl[j][0]]*wf[j][0]), wk0, a);
        a = fmaf(fmaf(xr[bl[j][1]+1], wc[j][1], xr[bl[j][1]]*wf[j][1]), wk1, a);
        a = fmaf(fmaf(xr[bl[j][2]+1], wc[j][2], xr[bl[j][2]]*wf[j][2]), wk2, a);
        a = fmaf(fmaf(xr[bl[j][3]+1], wc[j][3], xr[bl[j][3]]*wf[j][3]), wk3, a);
        a = fmaf(fmaf(xr[bl[j][4]+1], wc[j][4], xr[bl[j][4]]*wf[j][4]), wk4, a);
        o[j] = a;
      }
      size_t op = ((size_t)b*CHN + cu)*TLEN + t0 + tx;
      out[op]      = o[0];
      out[op + 64] = o[1];
      if (WDT) {
        union { bf16 h; unsigned short u; } cv0, cv1;
        cv0.h = __float2bfloat16(o[0]);
        cv1.h = __float2bfloat16(o[1]);
        if (i & 1) { pk0[i>>1] |= (unsigned)cv0.u << 16;
                     pk1[i>>1] |= (unsigned)cv1.u << 16; }
        else       { pk0[i>>1]  = cv0.u;  pk1[i>>1]  = cv1.u; }
      }
    }
  }

  if (WDT) {
    // thread's 16 bf16 are ci-contiguous: chunk (b,ch), row t+1, col half
    int ch   = blockIdx.y >> 1;
    int colb = (blockIdx.y & 1)*16;
    bf16* p0 = dt + (size_t)(b*16 + ch)*DT_CHUNK
                  + (size_t)(t0 + tx + 1)*32 + colb;
    *(uint4*)p0       = make_uint4(pk0[0], pk0[1], pk0[2], pk0[3]);
    *((uint4*)p0 + 1) = make_uint4(pk0[4], pk0[5], pk0[6], pk0[7]);
    bf16* p1 = p0 + 64*32;
    *(uint4*)p1       = make_uint4(pk1[0], pk1[1], pk1[2], pk1[3]);
    *((uint4*)p1 + 1) = make_uint4(pk1[4], pk1[5], pk1[6], pk1[7]);
  }
}

// ---------------------------------------------------------------------------
// k2d: fused rp1(conv3, 512->256)+ReLU+rp2(256->1)+bias, bf16 MFMA.
// BOTH operands staged by pure global_load_lds DMA (Ws from w1t, Dt from
// dtile -- no loads/cvt/ds_write in the loop). Double-buffered, 2 blocks/CU
// (LDS 64.8 KB). BM=64 (co-quarter, grid y=4), BN=256, 256 thr (4 waves).
// Per iter: issue next Ws+Dt DMA -> COMPUTE(cur) hides DMA latency ->
// single barrier. Partial co-sums atomicAdd into outs (pre-set to b2).
// ---------------------------------------------------------------------------
#define DMA_W2(dst, ch_) do {                                                  \
  const char* gs = (const char*)(w1t + (size_t)((ch_)*4 + m0)*7680);           \
  char* ld = (char*)&Ws[dst][0];                                               \
  for (int of = tid*16; of < 15360; of += 4096) {                              \
    __builtin_amdgcn_global_load_lds(                                          \
        (const __attribute__((address_space(1))) unsigned int*)(gs + of),      \
        (__attribute__((address_space(3))) unsigned int*)(ld + of), 16, 0, 0); \
  }                                                                            \
} while(0)

#define DMA_D2(dst, ch_) do {                                                  \
  const char* gs = (const char*)(dt + (size_t)(b*16 + (ch_))*DT_CHUNK          \
                                    + (size_t)t0*32);                          \
  char* ld = (char*)&Dt[dst][0];                                               \
  for (int of = tid*16; of < 16512; of += 4096) {                              \
    __builtin_amdgcn_global_load_lds(                                          \
        (const __attribute__((address_space(1))) unsigned int*)(gs + of),      \
        (__attribute__((address_space(3))) unsigned int*)(ld + of), 16, 0, 0); \
  }                                                                            \
} while(0)

#define COMPUTE2(cur) do {                                                     \
  _Pragma("unroll")                                                            \
  for (int r=0;r<3;++r) {                                                      \
    bf16x8 af[4], bfr[4];                                                      \
    _Pragma("unroll")                                                          \
    for (int mt=0;mt<4;++mt)                                                   \
      af[mt] = *(const bf16x8*)&Ws[cur][(size_t)(r*64 + mt*16 + ln15)*40 + quad*8];\
    _Pragma("unroll")                                                          \
    for (int nt=0;nt<4;++nt)                                                   \
      bfr[nt] = *(const bf16x8*)&Dt[cur][(size_t)(wN*64 + nt*16 + ln15 + r)*32 + quad*8];\
    _Pragma("unroll")                                                          \
    for (int mt=0;mt<4;++mt)                                                   \
      _Pragma("unroll")                                                        \
      for (int nt=0;nt<4;++nt)                                                 \
        acc[mt][nt] = __builtin_amdgcn_mfma_f32_16x16x32_bf16(                 \
            af[mt], bfr[nt], acc[mt][nt], 0, 0, 0);                            \
  }                                                                            \
} while(0)

__global__ __launch_bounds__(256, 2) void k2d(const bf16* __restrict__ dt,
    const bf16* __restrict__ w1t, const float* __restrict__ b1,
    const float* __restrict__ w2, float* __restrict__ outs)
{
  int n0 = blockIdx.x*256;         // BN=256 (divides TLEN)
  int m0 = blockIdx.y;             // 0..3: co quarter
  int b  = n0 / TLEN;
  int t0 = n0 % TLEN;
  int tid  = threadIdx.x;          // 0..255
  int lane = tid & 63;
  int wN   = tid >> 6;             // wave 0..3 = 64-col n group
  int ln15 = lane & 15, quad = lane >> 4;

  __shared__ bf16 Ws[2][3*64*40];  // 30,720 B
  __shared__ bf16 Dt[2][258*32];   // 33,024 B
  __shared__ float Ss[256];

  f32x4 acc[4][4];
  #pragma unroll
  for (int i=0;i<4;++i)
    #pragma unroll
    for (int j=0;j<4;++j) acc[i][j] = (f32x4){0.f,0.f,0.f,0.f};

  // prologue: stage ch=0 into buffer 0
  DMA_W2(0, 0);
  DMA_D2(0, 0);
  __syncthreads();                 // drains DMA (vmcnt)

  for (int ch=0; ch<16; ++ch) {
    int cur = ch & 1;
    int nxt = cur ^ 1;
    if (ch < 15) {                 // issue next chunk early (uniform branch)
      DMA_W2(nxt, ch+1);
      DMA_D2(nxt, ch+1);
    }
    COMPUTE2(cur);                 // ds_read + MFMA hide the in-flight DMA
    __syncthreads();               // one barrier/iter; drains nxt DMA
  }

  // epilogue: strength[n] += sum_{co in quarter} relu(H[co][n]+b1[co])*w2[co]
  float part[4] = {0.f,0.f,0.f,0.f};
  #pragma unroll
  for (int mt=0;mt<4;++mt) {
    #pragma unroll
    for (int rr=0;rr<4;++rr) {
      int row = m0*64 + mt*16 + quad*4 + rr;
      float bias = b1[row];
      float wv   = w2[row];
      #pragma unroll
      for (int nt=0;nt<4;++nt) {
        float h = acc[mt][nt][rr] + bias;
        h = fmaxf(h, 0.f);
        part[nt] = fmaf(h, wv, part[nt]);
      }
    }
  }
  Ss[tid] = 0.f;
  __syncthreads();
  #pragma unroll
  for (int nt=0;nt<4;++nt)
    atomicAdd(&Ss[wN*64 + nt*16 + ln15], part[nt]);
  __syncthreads();
  atomicAdd(&outs[n0 + tid], Ss[tid]);
}

// ---------------------------------------------------------------------------
// k2r: R5 fallback (register-staged def) -- used only if ws too small for
// dtile. Identical to the R5-measured 51.9us kernel.
// ---------------------------------------------------------------------------
#define DMA_WSR(dst, ch_) do {                                                 \
  const char* gs = (const char*)(w1t + (size_t)((ch_)*4 + m0)*7680);           \
  char* ld = (char*)&Ws[dst][0];                                               \
  for (int of = tid*16; of < 15360; of += 4096) {                              \
    __builtin_amdgcn_global_load_lds(                                          \
        (const __attribute__((address_space(1))) unsigned int*)(gs + of),      \
        (__attribute__((address_space(3))) unsigned int*)(ld + of), 16, 0, 0); \
  }                                                                            \
} while(0)

#define LOAD_DTR(ch_) do {                                                     \
  const float* dpb = def + ((size_t)b*CHN + (ch_)*32 + g*8)*TLEN;              \
  _Pragma("unroll")                                                            \
  for (int s=0;s<4;++s) {                                                      \
    int t = t0 - 1 + tl + s*64;                                                \
    _Pragma("unroll")                                                          \
    for (int j=0;j<8;++j)                                                      \
      rg[s][j] = (t>=0 && t<TLEN) ? dpb[(size_t)j*TLEN + t] : 0.f;             \
  }                                                                            \
  if (tl < 2) {                                                                \
    int t = t0 - 1 + 256 + tl;                                                 \
    _Pragma("unroll")                                                          \
    for (int j=0;j<8;++j)                                                      \
      rt[j] = (t<TLEN) ? dpb[(size_t)j*TLEN + t] : 0.f;                        \
  }                                                                            \
} while(0)

#define WRITE_DTR(dst) do {                                                    \
  _Pragma("unroll")                                                            \
  for (int s=0;s<4;++s) {                                                      \
    bf16x8 v;                                                                  \
    _Pragma("unroll")                                                          \
    for (int j=0;j<8;++j) { union{bf16 h; short u;} cv;                        \
      cv.h = __float2bfloat16(rg[s][j]); v[j] = cv.u; }                        \
    *(bf16x8*)((char*)&Dt[dst][0] + (tl + s*64)*80 + g*16) = v;                \
  }                                                                            \
  if (tl < 2) {                                                                \
    bf16x8 v;                                                                  \
    _Pragma("unroll")                                                          \
    for (int j=0;j<8;++j) { union{bf16 h; short u;} cv;                        \
      cv.h = __float2bfloat16(rt[j]); v[j] = cv.u; }                           \
    *(bf16x8*)((char*)&Dt[dst][0] + (256 + tl)*80 + g*16) = v;                 \
  }                                                                            \
} while(0)

#define COMPUTER(cur) do {                                                     \
  _Pragma("unroll")                                                            \
  for (int r=0;r<3;++r) {                                                      \
    bf16x8 af[4], bfr[4];                                                      \
    _Pragma("unroll")                                                          \
    for (int mt=0;mt<4;++mt)                                                   \
      af[mt] = *(const bf16x8*)&Ws[cur][(size_t)(r*64 + mt*16 + ln15)*40 + quad*8];\
    _Pragma("unroll")                                                          \
    for (int nt=0;nt<4;++nt)                                                   \
      bfr[nt] = *(const bf16x8*)&Dt[cur][(size_t)(wN*64 + nt*16 + ln15 + r)*40 + quad*8];\
    _Pragma("unroll")                                                          \
    for (int mt=0;mt<4;++mt)                                                   \
      _Pragma("unroll")                                                        \
      for (int nt=0;nt<4;++nt)                                                 \
        acc[mt][nt] = __builtin_amdgcn_mfma_f32_16x16x32_bf16(                 \
            af[mt], bfr[nt], acc[mt][nt], 0, 0, 0);                            \
  }                                                                            \
} while(0)

__global__ __launch_bounds__(256, 2) void k2r(const float* __restrict__ def,
    const bf16* __restrict__ w1t, const float* __restrict__ b1,
    const float* __restrict__ w2, float* __restrict__ outs)
{
  int n0 = blockIdx.x*256;
  int m0 = blockIdx.y;
  int b  = n0 / TLEN;
  int t0 = n0 % TLEN;
  int tid  = threadIdx.x;
  int lane = tid & 63;
  int wN   = tid >> 6;
  int ln15 = lane & 15, quad = lane >> 4;

  __shared__ bf16 Ws[2][3*64*40];
  __shared__ bf16 Dt[2][258*40];
  __shared__ float Ss[256];

  int g  = tid >> 6;
  int tl = tid & 63;

  f32x4 acc[4][4];
  #pragma unroll
  for (int i=0;i<4;++i)
    #pragma unroll
    for (int j=0;j<4;++j) acc[i][j] = (f32x4){0.f,0.f,0.f,0.f};

  float rg[4][8], rt[8];
  #pragma unroll
  for (int j=0;j<8;++j) rt[j] = 0.f;

  DMA_WSR(0, 0);
  LOAD_DTR(0);
  WRITE_DTR(0);
  __syncthreads();

  for (int ch=0; ch<16; ++ch) {
    int cur = ch & 1;
    int nxt = cur ^ 1;
    if (ch < 15) {
      DMA_WSR(nxt, ch+1);
      LOAD_DTR(ch+1);
    }
    COMPUTER(cur);
    if (ch < 15)
      WRITE_DTR(nxt);
    __syncthreads();
  }

  float part[4] = {0.f,0.f,0.f,0.f};
  #pragma unroll
  for (int mt=0;mt<4;++mt) {
    #pragma unroll
    for (int rr=0;rr<4;++rr) {
      int row = m0*64 + mt*16 + quad*4 + rr;
      float bias = b1[row];
      float wv   = w2[row];
      #pragma unroll
      for (int nt=0;nt<4;++nt) {
        float h = acc[mt][nt][rr] + bias;
        h = fmaxf(h, 0.f);
        part[nt] = fmaf(h, wv, part[nt]);
      }
    }
  }
  Ss[tid] = 0.f;
  __syncthreads();
  #pragma unroll
  for (int nt=0;nt<4;++nt)
    atomicAdd(&Ss[wN*64 + nt*16 + ln15], part[nt]);
  __syncthreads();
  atomicAdd(&outs[n0 + tid], Ss[tid]);
}

extern "C" void kernel_launch(void* const* d_in, const int* in_sizes, int n_in,
                              void* d_out, int out_size, void* d_ws, size_t ws_size,
                              hipStream_t stream) {
  const float* x  = (const float*)d_in[0];
  const float* ow = (const float*)d_in[1];
  const float* ob = (const float*)d_in[2];
  const float* mw = (const float*)d_in[3];
  const float* mb = (const float*)d_in[4];
  const float* wg = (const float*)d_in[5];
  const float* w1 = (const float*)d_in[6];
  const float* b1 = (const float*)d_in[7];
  const float* w2 = (const float*)d_in[8];
  const float* b2 = (const float*)d_in[9];

  float* out_def = (float*)d_out;
  float* out_str = out_def + (size_t)BATCH*CHN*TLEN;

  float2* samp = (float2*)d_ws;                                  // 1.31 MB
  bf16*   w1t  = (bf16*)((char*)d_ws + SAMP_BYTES);              // 983 KB
  float*  wpk  = (float*)((char*)d_ws + SAMP_BYTES + W1T_BYTES); // 64 KB

  size_t need = (size_t)SAMP_BYTES + W1T_BYTES + WPK_BYTES + DT_BYTES;
  bf16* dt = (ws_size >= need)
      ? (bf16*)((char*)d_ws + SAMP_BYTES + W1T_BYTES + WPK_BYTES)
      : nullptr;

  kPrep<<<dim3(W1T_ELEMS/256 + 256), 256, 0, stream>>>(
      w1, w1t, ow, mw, wpk, out_str, b2, dt);
  kS   <<<dim3(TLEN/64, BATCH), dim3(64,8), 0, stream>>>(x, wpk, ob, mb, samp);
  if (dt) {
    kDf<true> <<<dim3(TLEN/BT, CHN/16, BATCH), 64, 0, stream>>>(
        x, wg, samp, out_def, dt);
    k2d<<<dim3(BATCH*TLEN/256, 4), 256, 0, stream>>>(dt, w1t, b1, w2, out_str);
  } else {
    kDf<false><<<dim3(TLEN/BT, CHN/16, BATCH), 64, 0, stream>>>(
        x, wg, samp, out_def, nullptr);
    k2r<<<dim3(BATCH*TLEN/256, 4), 256, 0, stream>>>(out_def, w1t, b1, w2, out_str);
  }
}